// Round 3
// baseline (320.912 us; speedup 1.0000x reference)
//
#include <hip/hip_runtime.h>

typedef unsigned short u16;
using bf16x8 = __attribute__((ext_vector_type(8))) short;
using f32x4  = __attribute__((ext_vector_type(4))) float;

#define DEV __device__ __forceinline__

// ---- constants ----
// B=16, C=384, H=W=32 -> N=1024 tokens per batch, 16384 total. heads=8, hd=48 (padded to 64).
constexpr int    NTOK = 16384;
constexpr size_t QKSZ = (size_t)16 * 8 * 1024 * 64; // elements per Q / K / Vt buffer (8388608)
constexpr float  ATTN_SCALE = 0.14433756729740645f; // 48^-0.5 (folded into Q weights at cvt)

DEV u16 f2bf(float x) {                 // f32 -> bf16 RNE
  unsigned int u = __float_as_uint(x);
  u += 0x7fffu + ((u >> 16) & 1u);
  return (u16)(u >> 16);
}

DEV void async16(const u16* g, u16* l) { // global -> LDS direct, 16B per lane
  __builtin_amdgcn_global_load_lds(
      (const __attribute__((address_space(1))) unsigned int*)g,
      (__attribute__((address_space(3))) unsigned int*)l, 16, 0, 0);
}

// swizzled LDS read for attn [rows][64 bf16] tiles (128B row): byte ^= (row&7)<<4
DEV const bf16x8* lds_swz(const u16* base, int row, int bytecol) {
  int byte = row * 128 + bytecol;
  byte ^= (row & 7) << 4;
  return (const bf16x8*)((const char*)base + byte);
}

// fast exact-enough GELU: tanh form via one exp; |err| < ~3.5e-4 abs
DEV float gelu_f(float x) {
  float y = 0.7978845608028654f * (x + 0.044715f * x * x * x);
  float e = __expf(2.f * y);
  float t = 1.f - 2.f / (e + 1.f);
  return 0.5f * x * (1.f + t);
}

// ---- weight convert + QKV padding (d 48..63 zero, ATTN_SCALE folded into Q rows/bias) ----
__global__ void cvt_kernel(const float* __restrict__ qkvw, const float* __restrict__ qkvb,
                           const float* __restrict__ projw, const float* __restrict__ fc1w,
                           const float* __restrict__ fc2w,
                           u16* __restrict__ wqkvp, float* __restrict__ biasp,
                           u16* __restrict__ wproj, u16* __restrict__ wfc1,
                           u16* __restrict__ wfc2) {
  int i = blockIdx.x * 256 + threadIdx.x;  // quad index
  if (i < 147456) {                        // padded qkv weight [1536][384]
    int p = i / 96, q = (i - p * 96) * 4;
    int which = p >> 9, h = (p >> 6) & 7, d = p & 63;
    ushort4 o{0, 0, 0, 0};
    if (d < 48) {
      float sc = which ? 1.f : ATTN_SCALE;
      float4 v = *(const float4*)(qkvw + (size_t)(which * 384 + h * 48 + d) * 384 + q);
      o = ushort4{f2bf(v.x * sc), f2bf(v.y * sc), f2bf(v.z * sc), f2bf(v.w * sc)};
    }
    *(ushort4*)(wqkvp + (size_t)p * 384 + q) = o;
  } else if (i < 479232) {                 // plain converts
    const float* s; u16* d; int off;
    if (i < 184320)      { s = projw; d = wproj; off = i - 147456; }
    else if (i < 331776) { s = fc1w;  d = wfc1;  off = i - 184320; }
    else                 { s = fc2w;  d = wfc2;  off = i - 331776; }
    float4 v = *(const float4*)(s + (size_t)off * 4);
    *(ushort4*)(d + (size_t)off * 4) = ushort4{f2bf(v.x), f2bf(v.y), f2bf(v.z), f2bf(v.w)};
  } else if (i < 479616) {                 // padded qkv bias [1536] f32
    int qi = (i - 479232) * 4;
    float4 o;
    float* op = (float*)&o;
#pragma unroll
    for (int r = 0; r < 4; ++r) {
      int p = qi + r, which = p >> 9, h = (p >> 6) & 7, d = p & 63;
      op[r] = (d < 48) ? qkvb[which * 384 + h * 48 + d] * (which ? 1.f : ATTN_SCALE) : 0.f;
    }
    *(float4*)(biasp + qi) = o;
  }
}

// ---- LayerNorm over C=384 with transpose: in (B, 384, 1024) f32 -> out (B*1024, 384) bf16 ----
__global__ __launch_bounds__(256) void ln_kernel(
    const float* __restrict__ in, const float* __restrict__ gw,
    const float* __restrict__ gb, u16* __restrict__ out) {
  __shared__ float tile[32][385];
  __shared__ float mu_s[32], rs_s[32];
  const int b = blockIdx.y;
  const int n0 = blockIdx.x * 32;
  const int t = threadIdx.x;
  const int j = t & 31, cb = t >> 5;
  const float* src = in + (size_t)b * 384 * 1024 + n0;
  for (int k = 0; k < 48; ++k) {
    int c = k * 8 + cb;
    tile[j][c] = src[(size_t)c * 1024 + j];   // coalesced along n
  }
  __syncthreads();
  const int jt = t >> 3, r = t & 7;           // 8 threads per token
  float s = 0.f, ss = 0.f;
  for (int c = r; c < 384; c += 8) { float v = tile[jt][c]; s += v; ss += v * v; }
  s += __shfl_xor(s, 1); ss += __shfl_xor(ss, 1);
  s += __shfl_xor(s, 2); ss += __shfl_xor(ss, 2);
  s += __shfl_xor(s, 4); ss += __shfl_xor(ss, 4);
  const float mean = s * (1.f / 384.f);
  const float var  = ss * (1.f / 384.f) - mean * mean;  // ddof=0
  if (r == 0) { mu_s[jt] = mean; rs_s[jt] = rsqrtf(var + 1e-5f); }
  __syncthreads();
  for (int q = t; q < 3072; q += 256) {       // 32 tokens x 96 ushort4 quads
    int tok = q / 96, c4 = (q - tok * 96) * 4;
    float m = mu_s[tok], rv = rs_s[tok];
    float4 wv = *(const float4*)(gw + c4);
    float4 bv = *(const float4*)(gb + c4);
    u16* dst = out + (size_t)(b * 1024 + n0 + tok) * 384 + c4;
    ushort4 o{f2bf((tile[tok][c4 + 0] - m) * rv * wv.x + bv.x),
              f2bf((tile[tok][c4 + 1] - m) * rv * wv.y + bv.y),
              f2bf((tile[tok][c4 + 2] - m) * rv * wv.z + bv.z),
              f2bf((tile[tok][c4 + 3] - m) * rv * wv.w + bv.w)};
    *(ushort4*)dst = o;
  }
}

// ---- generic bf16 MFMA GEMM: out[m, o] = sum_k A[m,k] * W[o,k] (+bias, epilogue variants) ----
// 128x128 tile, BK=32, 3-buffer counted-vmcnt pipeline, T2-swizzled LDS.
// EPI 0: QK of padded QKV (cols 0..1023), SWAPPED operands, 8B stores to Q/K [bh,n,64]
// EPI 4: V  of padded QKV (cols 1024..1535), normal, 8B stores to Vt [bh,64,n]
// EPI 1: += resid (x, (B,C,N) read) -> outf (B,C,N) f32                [proj]
// EPI 2: GELU, SWAPPED operands -> outh bf16 row-major (M x 1536)      [fc1]
// EPI 3: += resid (y1t (B,C,N)) -> outf = d_out (B,C,N) f32            [fc2]
template<int EPI>
__global__ __launch_bounds__(256, 3) void gemm_kernel(
    const u16* __restrict__ A, const u16* __restrict__ W,
    const float* __restrict__ bias, float* __restrict__ outf,
    u16* __restrict__ outh, const float* __restrict__ resid, int K) {
  constexpr bool SWAP = (EPI == 0 || EPI == 2);
  __shared__ u16 sA[3][4096], sB[3][4096];  // 128x32 bf16 each, triple buffered
  const int m0 = blockIdx.x * 128;
  const int n0 = (EPI == 4 ? 1024 : 0) + blockIdx.y * 128;
  const int wv = threadIdx.x >> 6, lane = threadIdx.x & 63;
  const int wm = (wv >> 1) * 64, wn = (wv & 1) * 64;
  const int l16 = lane & 15, lg = lane >> 4;
  const int rsw = (lg ^ (l16 & 3)) << 4;     // swizzled 16B slot for fragment reads

  f32x4 acc[4][4];
#pragma unroll
  for (int i = 0; i < 4; ++i)
#pragma unroll
    for (int jj = 0; jj < 4; ++jj) acc[i][jj] = f32x4{0.f, 0.f, 0.f, 0.f};

  const int nk = K >> 5;
  auto stage = [&](int buf, int kt) {
    const u16* Ab = A + (size_t)m0 * K + kt * 32;
    const u16* Wb = W + (size_t)n0 * K + kt * 32;
#pragma unroll
    for (int i = 0; i < 2; ++i) {
      int chunk = i * 256 + wv * 64 + lane;     // 512 chunks of 16B per tile
      int row = chunk >> 2, sl = (chunk & 3) ^ (row & 3);  // pre-swizzled source
      async16(Ab + (size_t)row * K + sl * 8, &sA[buf][(i * 256 + wv * 64) * 8]);
      async16(Wb + (size_t)row * K + sl * 8, &sB[buf][(i * 256 + wv * 64) * 8]);
    }
  };
  stage(0, 0);
  stage(1, 1);
  int buf = 0;
  for (int kt = 0; kt < nk; ++kt) {
    if (kt < nk - 1) asm volatile("s_waitcnt vmcnt(4)" ::: "memory");
    else             asm volatile("s_waitcnt vmcnt(0)" ::: "memory");
    __builtin_amdgcn_s_barrier();
    if (kt + 2 < nk) { int nb = buf + 2; if (nb >= 3) nb -= 3; stage(nb, kt + 2); }
    bf16x8 av[4], bv[4];
#pragma unroll
    for (int f = 0; f < 4; ++f) {
      av[f] = *(const bf16x8*)((const char*)&sA[buf][0] + (wm + f * 16 + l16) * 64 + rsw);
      bv[f] = *(const bf16x8*)((const char*)&sB[buf][0] + (wn + f * 16 + l16) * 64 + rsw);
    }
    __builtin_amdgcn_s_setprio(1);
#pragma unroll
    for (int mf = 0; mf < 4; ++mf)
#pragma unroll
      for (int nf = 0; nf < 4; ++nf) {
        if constexpr (SWAP)
          acc[mf][nf] = __builtin_amdgcn_mfma_f32_16x16x32_bf16(bv[nf], av[mf], acc[mf][nf], 0, 0, 0);
        else
          acc[mf][nf] = __builtin_amdgcn_mfma_f32_16x16x32_bf16(av[mf], bv[nf], acc[mf][nf], 0, 0, 0);
      }
    __builtin_amdgcn_s_setprio(0);
    ++buf; if (buf >= 3) buf = 0;
  }

  if constexpr (SWAP) {
    // D: reg-dim = W cols (4 consecutive), lane l16 = token
#pragma unroll
    for (int mf = 0; mf < 4; ++mf) {
      const int token = m0 + wm + mf * 16 + l16;
      const int b = token >> 10, nn = token & 1023;
#pragma unroll
      for (int nf = 0; nf < 4; ++nf) {
        const int col = n0 + wn + nf * 16 + lg * 4;   // +reg
        f32x4 v = acc[mf][nf];
        float4 bb = *(const float4*)(bias + col);
        unsigned long long pk = 0;
        if constexpr (EPI == 0) {
#pragma unroll
          for (int rr = 0; rr < 4; ++rr)
            pk |= (unsigned long long)f2bf(v[rr] + ((const float*)&bb)[rr]) << (16 * rr);
          const int which = col >> 9, h = (col >> 6) & 7, d0 = col & 63;
          size_t idx = (size_t)which * QKSZ + (size_t)((b * 8 + h) * 1024 + nn) * 64 + d0;
          *(unsigned long long*)&outh[idx] = pk;
        } else { // EPI 2: GELU, row-major [token][1536]
#pragma unroll
          for (int rr = 0; rr < 4; ++rr)
            pk |= (unsigned long long)f2bf(gelu_f(v[rr] + ((const float*)&bb)[rr])) << (16 * rr);
          *(unsigned long long*)&outh[(size_t)token * 1536 + col] = pk;
        }
      }
    }
  } else {
    // D: reg-dim = tokens (4 consecutive), lane l16 = W col
#pragma unroll
    for (int mf = 0; mf < 4; ++mf) {
      const int mm = m0 + wm + mf * 16 + lg * 4;      // token base
      const int b = mm >> 10, nn = mm & 1023;
#pragma unroll
      for (int nf = 0; nf < 4; ++nf) {
        const int col = n0 + wn + nf * 16 + l16;
        f32x4 v = acc[mf][nf];
        const float bs = bias[col];
        if constexpr (EPI == 4) {  // V -> Vt [bh][d][n], 4 consecutive n = 8B store
          unsigned long long pk = 0;
#pragma unroll
          for (int rr = 0; rr < 4; ++rr)
            pk |= (unsigned long long)f2bf(v[rr] + bs) << (16 * rr);
          const int h = (col >> 6) & 7, d = col & 63;
          size_t idx = 2ull * QKSZ + (((size_t)((b * 8 + h) * 64 + d)) << 10) + nn;
          *(unsigned long long*)&outh[idx] = pk;
        } else {  // EPI 1 / 3: residual add, (B,C,N) f32, n fast -> float4
          size_t idx = ((size_t)(b * 384 + col) << 10) + nn;
          float4 rr4 = *(const float4*)&resid[idx];
          float4 o{v[0] + bs + rr4.x, v[1] + bs + rr4.y, v[2] + bs + rr4.z, v[3] + bs + rr4.w};
          *(float4*)&outf[idx] = o;
        }
      }
    }
  }
}

// ---- flash attention: Q(scaled) [bh,n,64] x K [bh,n,64] -> softmax -> V^T [bh,64,n] ----
// 1024 blocks = 128 (b,h) x 8 q-tiles of 128 rows. 4 waves, 32 q-rows each. KV tile = 64.
// 3-buffer counted-vmcnt pipeline; XOR-swizzled K/V/Q; no online max (logits bounded).
__global__ __launch_bounds__(256, 2) void attn_kernel(
    const u16* __restrict__ Qg, const u16* __restrict__ Kg,
    const u16* __restrict__ Vtg, u16* __restrict__ outp) {
  __shared__ u16 Ks[3][4096];
  __shared__ u16 Vs[3][4096];
  __shared__ u16 QPs[4 * 32 * 72]; // Q staging (8192 u16) then per-wave P tiles (stride 72)
  const int orig = blockIdx.x;
  const int swz = (orig & 7) * 128 + (orig >> 3);   // XCD swizzle: 8 q-tiles of a bh share an XCD
  const int bh = swz >> 3, qt = swz & 7;
  const int w = threadIdx.x >> 6, lane = threadIdx.x & 63;
  const int l16 = lane & 15, lg = lane >> 4;

  const u16* kbase = Kg + (size_t)bh * 1024 * 64;
  const u16* vbase = Vtg + (size_t)bh * 64 * 1024;

  auto stageKV = [&](int buf, int kv) {
#pragma unroll
    for (int i = 0; i < 2; ++i) {
      int cb = (i * 4 + w) * 64;
      int ck = cb + lane;
      int g  = ck ^ ((ck >> 3) & 7);              // inverse swizzle on the SOURCE
      async16(kbase + (size_t)kv * 4096 + g * 8, &Ks[buf][cb * 8]);
      async16(vbase + (size_t)(g >> 3) * 1024 + kv * 64 + (g & 7) * 8, &Vs[buf][cb * 8]);
    }
  };

  { // stage Q tile 128x64 (contiguous in global), swizzled
    const u16* src = Qg + (size_t)(bh * 1024 + qt * 128) * 64;
#pragma unroll
    for (int i = 0; i < 4; ++i) {
      int cb = (i * 4 + w) * 64;
      int ck = cb + lane;
      int g  = ck ^ ((ck >> 3) & 7);
      async16(src + g * 8, &QPs[cb * 8]);
    }
  }
  stageKV(0, 0);
  stageKV(1, 1);
  asm volatile("s_waitcnt vmcnt(8)" ::: "memory");  // Q done
  __builtin_amdgcn_s_barrier();

  bf16x8 qf[2][2];
#pragma unroll
  for (int mf = 0; mf < 2; ++mf)
#pragma unroll
    for (int ks = 0; ks < 2; ++ks)
      qf[mf][ks] = *lds_swz(QPs, w * 32 + mf * 16 + l16, ks * 64 + lg * 16);
  asm volatile("s_waitcnt lgkmcnt(0)" ::: "memory");
  __builtin_amdgcn_s_barrier();  // all Q reads done before QPs is reused for P

  float lr[2][4];
  f32x4 acco[2][4];
#pragma unroll
  for (int mf = 0; mf < 2; ++mf) {
#pragma unroll
    for (int r = 0; r < 4; ++r) lr[mf][r] = 0.f;
#pragma unroll
    for (int df = 0; df < 4; ++df) acco[mf][df] = f32x4{0.f, 0.f, 0.f, 0.f};
  }
  u16* Pw = &QPs[w * 32 * 72];

  auto compute = [&](int buf) {
    f32x4 accs[2][4];
#pragma unroll
    for (int mf = 0; mf < 2; ++mf)
#pragma unroll
      for (int nf = 0; nf < 4; ++nf) accs[mf][nf] = f32x4{0.f, 0.f, 0.f, 0.f};
    __builtin_amdgcn_s_setprio(1);
#pragma unroll
    for (int nf = 0; nf < 4; ++nf) {
      bf16x8 k0 = *lds_swz(Ks[buf], nf * 16 + l16, lg * 16);
      bf16x8 k1 = *lds_swz(Ks[buf], nf * 16 + l16, 64 + lg * 16);
#pragma unroll
      for (int mf = 0; mf < 2; ++mf) {
        accs[mf][nf] = __builtin_amdgcn_mfma_f32_16x16x32_bf16(qf[mf][0], k0, accs[mf][nf], 0, 0, 0);
        accs[mf][nf] = __builtin_amdgcn_mfma_f32_16x16x32_bf16(qf[mf][1], k1, accs[mf][nf], 0, 0, 0);
      }
    }
    __builtin_amdgcn_s_setprio(0);
    // softmax numerator: p = exp(S) (scale pre-folded into Q, logits bounded)
#pragma unroll
    for (int mf = 0; mf < 2; ++mf)
#pragma unroll
      for (int r = 0; r < 4; ++r) {
        float s0 = __expf(accs[mf][0][r]);
        float s1 = __expf(accs[mf][1][r]);
        float s2 = __expf(accs[mf][2][r]);
        float s3 = __expf(accs[mf][3][r]);
        accs[mf][0][r] = s0; accs[mf][1][r] = s1;
        accs[mf][2][r] = s2; accs[mf][3][r] = s3;
        lr[mf][r] += s0 + s1 + s2 + s3;          // in-lane partial; cross-lane reduce at end
      }
    // write P (C-layout) to LDS, re-read in A-layout for PV
#pragma unroll
    for (int mf = 0; mf < 2; ++mf)
#pragma unroll
      for (int nf = 0; nf < 4; ++nf)
#pragma unroll
        for (int r = 0; r < 4; ++r)
          Pw[(mf * 16 + lg * 4 + r) * 72 + nf * 16 + l16] = f2bf(accs[mf][nf][r]);
    asm volatile("s_waitcnt lgkmcnt(0)" ::: "memory");
#pragma unroll
    for (int ks = 0; ks < 2; ++ks) {
      bf16x8 pa[2], vf[4];
#pragma unroll
      for (int mf = 0; mf < 2; ++mf)
        pa[mf] = *(const bf16x8*)&Pw[(mf * 16 + l16) * 72 + ks * 32 + lg * 8];
#pragma unroll
      for (int df = 0; df < 4; ++df)
        vf[df] = *lds_swz(Vs[buf], df * 16 + l16, ks * 64 + lg * 16);
      __builtin_amdgcn_s_setprio(1);
#pragma unroll
      for (int mf = 0; mf < 2; ++mf)
#pragma unroll
        for (int df = 0; df < 4; ++df)
          acco[mf][df] = __builtin_amdgcn_mfma_f32_16x16x32_bf16(pa[mf], vf[df], acco[mf][df], 0, 0, 0);
      __builtin_amdgcn_s_setprio(0);
    }
  };

  int buf = 0;
  for (int kv = 0; kv < 16; ++kv) {
    if (kv < 15) asm volatile("s_waitcnt vmcnt(4)" ::: "memory");
    else         asm volatile("s_waitcnt vmcnt(0)" ::: "memory");
    __builtin_amdgcn_s_barrier();
    if (kv + 2 < 16) { int nb = buf + 2; if (nb >= 3) nb -= 3; stageKV(nb, kv + 2); }
    compute(buf);
    ++buf; if (buf >= 3) buf = 0;
  }

  // epilogue: reduce l across the 16 cols, then out[(b*1024+token)*384 + h*48 + d], d < 48
  const int b = bh >> 3, h = bh & 7;
#pragma unroll
  for (int mf = 0; mf < 2; ++mf)
#pragma unroll
    for (int r = 0; r < 4; ++r) {
      float t = lr[mf][r];
      t += __shfl_xor(t, 1); t += __shfl_xor(t, 2);
      t += __shfl_xor(t, 4); t += __shfl_xor(t, 8);
      float inv = 1.f / t;
      int token = qt * 128 + w * 32 + mf * 16 + lg * 4 + r;
      size_t rowb = (size_t)(b * 1024 + token) * 384 + h * 48;
#pragma unroll
      for (int df = 0; df < 3; ++df)
        outp[rowb + df * 16 + l16] = f2bf(acco[mf][df][r] * inv);
    }
}

// ---- workspace layout (bytes) ----
constexpr size_t OFF_WQKVP = 0;          // 1536*384*2   = 1179648
constexpr size_t OFF_BIASP = 1179648;    // 1536*4      -> 1185792
constexpr size_t OFF_WPROJ = 1185792;    // 384*384*2   -> 1480704
constexpr size_t OFF_WFC1  = 1480704;    // 1536*384*2  -> 2660352
constexpr size_t OFF_WFC2  = 2660352;    // 384*1536*2  -> 3840000
constexpr size_t OFF_H     = 3840000;    // 16384*384*2 -> 16422912 (h1, later h2)
constexpr size_t OFF_QKV   = 16422912;   // 3*QKSZ*2    -> 66754560 (later f1)
constexpr size_t OFF_AO    = 66754560;   // 16384*384*2 -> 79337472
constexpr size_t OFF_Y1T   = 79337472;   // 16384*384*4 -> 104503296 total

extern "C" void kernel_launch(void* const* d_in, const int* in_sizes, int n_in,
                              void* d_out, int out_size, void* d_ws, size_t ws_size,
                              hipStream_t stream) {
  (void)in_sizes; (void)n_in; (void)out_size; (void)ws_size;
  const float* x     = (const float*)d_in[0];
  const float* ln1w  = (const float*)d_in[1];
  const float* ln1b  = (const float*)d_in[2];
  const float* qkvw  = (const float*)d_in[3];
  const float* qkvbi = (const float*)d_in[4];
  const float* projw = (const float*)d_in[5];
  const float* projb = (const float*)d_in[6];
  const float* ln2w  = (const float*)d_in[7];
  const float* ln2b  = (const float*)d_in[8];
  const float* fc1w  = (const float*)d_in[9];
  const float* fc1b  = (const float*)d_in[10];
  const float* fc2w  = (const float*)d_in[11];
  const float* fc2b  = (const float*)d_in[12];

  char* ws = (char*)d_ws;
  u16*   wqkvp = (u16*)(ws + OFF_WQKVP);
  float* biasp = (float*)(ws + OFF_BIASP);
  u16*   wproj = (u16*)(ws + OFF_WPROJ);
  u16*   wfc1  = (u16*)(ws + OFF_WFC1);
  u16*   wfc2  = (u16*)(ws + OFF_WFC2);
  u16*   h1    = (u16*)(ws + OFF_H);     // also h2
  u16*   qkvs  = (u16*)(ws + OFF_QKV);   // Q | K | Vt ; later f1
  u16*   f1    = qkvs;
  u16*   ao    = (u16*)(ws + OFF_AO);
  float* y1t   = (float*)(ws + OFF_Y1T);

  cvt_kernel<<<1874, 256, 0, stream>>>(qkvw, qkvbi, projw, fc1w, fc2w,
                                       wqkvp, biasp, wproj, wfc1, wfc2);

  dim3 lngrid(32, 16);
  ln_kernel<<<lngrid, 256, 0, stream>>>(x, ln1w, ln1b, h1);

  // QKV: QK tiles (swapped) + V tiles (normal->Vt); pads written as zeros, no memset
  gemm_kernel<0><<<dim3(NTOK / 128, 8), 256, 0, stream>>>(h1, wqkvp, biasp, nullptr, qkvs, nullptr, 384);
  gemm_kernel<4><<<dim3(NTOK / 128, 4), 256, 0, stream>>>(h1, wqkvp, biasp, nullptr, qkvs, nullptr, 384);

  attn_kernel<<<dim3(1024), 256, 0, stream>>>(qkvs, qkvs + QKSZ, qkvs + 2 * QKSZ, ao);

  gemm_kernel<1><<<dim3(NTOK / 128, 3), 256, 0, stream>>>(ao, wproj, projb, y1t, nullptr, x, 384);

  ln_kernel<<<lngrid, 256, 0, stream>>>(y1t, ln2w, ln2b, h1 /*h2*/);

  gemm_kernel<2><<<dim3(NTOK / 128, 12), 256, 0, stream>>>(h1, wfc1, fc1b, nullptr, f1, nullptr, 384);

  gemm_kernel<3><<<dim3(NTOK / 128, 3), 256, 0, stream>>>(f1, wfc2, fc2b, (float*)d_out, nullptr, y1t, 1536);
}

// Round 4
// 317.656 us; speedup vs baseline: 1.0102x; 1.0102x over previous
//
#include <hip/hip_runtime.h>

typedef unsigned short u16;
using bf16x8 = __attribute__((ext_vector_type(8))) short;
using f32x4  = __attribute__((ext_vector_type(4))) float;

#define DEV __device__ __forceinline__

// ---- constants ----
// B=16, C=384, H=W=32 -> N=1024 tokens per batch, 16384 total. heads=8, hd=48 (padded to 64).
constexpr int    NTOK = 16384;
constexpr size_t QKSZ = (size_t)16 * 8 * 1024 * 64; // elements per Q / K / Vt buffer (8388608)
constexpr float  ATTN_SCALE = 0.14433756729740645f; // 48^-0.5 (folded into Q weights at cvt)

DEV u16 f2bf(float x) {                 // f32 -> bf16 RNE
  unsigned int u = __float_as_uint(x);
  u += 0x7fffu + ((u >> 16) & 1u);
  return (u16)(u >> 16);
}

DEV void async16(const u16* g, u16* l) { // global -> LDS direct, 16B per lane (dest wave-uniform)
  __builtin_amdgcn_global_load_lds(
      (const __attribute__((address_space(1))) unsigned int*)g,
      (__attribute__((address_space(3))) unsigned int*)l, 16, 0, 0);
}

// swizzled LDS read for attn [rows][64 bf16] tiles (128B row): byte ^= (row&7)<<4
DEV const bf16x8* lds_swz(const u16* base, int row, int bytecol) {
  int byte = row * 128 + bytecol;
  byte ^= (row & 7) << 4;
  return (const bf16x8*)((const char*)base + byte);
}

// fast exact-enough GELU: tanh form via one exp; |err| < ~3.5e-4 abs
DEV float gelu_f(float x) {
  float y = 0.7978845608028654f * (x + 0.044715f * x * x * x);
  float e = __expf(2.f * y);
  float t = 1.f - 2.f / (e + 1.f);
  return 0.5f * x * (1.f + t);
}

// ---- weight convert + QKV padding (d 48..63 zero, ATTN_SCALE folded into Q rows/bias) ----
__global__ void cvt_kernel(const float* __restrict__ qkvw, const float* __restrict__ qkvb,
                           const float* __restrict__ projw, const float* __restrict__ fc1w,
                           const float* __restrict__ fc2w,
                           u16* __restrict__ wqkvp, float* __restrict__ biasp,
                           u16* __restrict__ wproj, u16* __restrict__ wfc1,
                           u16* __restrict__ wfc2) {
  int i = blockIdx.x * 256 + threadIdx.x;  // quad index
  if (i < 147456) {                        // padded qkv weight [1536][384]
    int p = i / 96, q = (i - p * 96) * 4;
    int which = p >> 9, h = (p >> 6) & 7, d = p & 63;
    ushort4 o{0, 0, 0, 0};
    if (d < 48) {
      float sc = which ? 1.f : ATTN_SCALE;
      float4 v = *(const float4*)(qkvw + (size_t)(which * 384 + h * 48 + d) * 384 + q);
      o = ushort4{f2bf(v.x * sc), f2bf(v.y * sc), f2bf(v.z * sc), f2bf(v.w * sc)};
    }
    *(ushort4*)(wqkvp + (size_t)p * 384 + q) = o;
  } else if (i < 479232) {                 // plain converts
    const float* s; u16* d; int off;
    if (i < 184320)      { s = projw; d = wproj; off = i - 147456; }
    else if (i < 331776) { s = fc1w;  d = wfc1;  off = i - 184320; }
    else                 { s = fc2w;  d = wfc2;  off = i - 331776; }
    float4 v = *(const float4*)(s + (size_t)off * 4);
    *(ushort4*)(d + (size_t)off * 4) = ushort4{f2bf(v.x), f2bf(v.y), f2bf(v.z), f2bf(v.w)};
  } else if (i < 479616) {                 // padded qkv bias [1536] f32
    int qi = (i - 479232) * 4;
    float4 o;
    float* op = (float*)&o;
#pragma unroll
    for (int r = 0; r < 4; ++r) {
      int p = qi + r, which = p >> 9, h = (p >> 6) & 7, d = p & 63;
      op[r] = (d < 48) ? qkvb[which * 384 + h * 48 + d] * (which ? 1.f : ATTN_SCALE) : 0.f;
    }
    *(float4*)(biasp + qi) = o;
  }
}

// ---- LayerNorm over C=384 with transpose: in (B, 384, 1024) f32 -> out (B*1024, 384) bf16 ----
__global__ __launch_bounds__(256) void ln_kernel(
    const float* __restrict__ in, const float* __restrict__ gw,
    const float* __restrict__ gb, u16* __restrict__ out) {
  __shared__ float tile[32][385];
  __shared__ float mu_s[32], rs_s[32];
  const int b = blockIdx.y;
  const int n0 = blockIdx.x * 32;
  const int t = threadIdx.x;
  const int j = t & 31, cb = t >> 5;
  const float* src = in + (size_t)b * 384 * 1024 + n0;
  for (int k = 0; k < 48; ++k) {
    int c = k * 8 + cb;
    tile[j][c] = src[(size_t)c * 1024 + j];   // coalesced along n
  }
  __syncthreads();
  const int jt = t >> 3, r = t & 7;           // 8 threads per token
  float s = 0.f, ss = 0.f;
  for (int c = r; c < 384; c += 8) { float v = tile[jt][c]; s += v; ss += v * v; }
  s += __shfl_xor(s, 1); ss += __shfl_xor(ss, 1);
  s += __shfl_xor(s, 2); ss += __shfl_xor(ss, 2);
  s += __shfl_xor(s, 4); ss += __shfl_xor(ss, 4);
  const float mean = s * (1.f / 384.f);
  const float var  = ss * (1.f / 384.f) - mean * mean;  // ddof=0
  if (r == 0) { mu_s[jt] = mean; rs_s[jt] = rsqrtf(var + 1e-5f); }
  __syncthreads();
  for (int q = t; q < 3072; q += 256) {       // 32 tokens x 96 ushort4 quads
    int tok = q / 96, c4 = (q - tok * 96) * 4;
    float m = mu_s[tok], rv = rs_s[tok];
    float4 wv = *(const float4*)(gw + c4);
    float4 bv = *(const float4*)(gb + c4);
    u16* dst = out + (size_t)(b * 1024 + n0 + tok) * 384 + c4;
    ushort4 o{f2bf((tile[tok][c4 + 0] - m) * rv * wv.x + bv.x),
              f2bf((tile[tok][c4 + 1] - m) * rv * wv.y + bv.y),
              f2bf((tile[tok][c4 + 2] - m) * rv * wv.z + bv.z),
              f2bf((tile[tok][c4 + 3] - m) * rv * wv.w + bv.w)};
    *(ushort4*)dst = o;
  }
}

// ---- 256x256 / BK=64 / 8-wave bf16 GEMM (T3-minimum pipeline, T2 perfect-quad swizzle) ----
// out[m,o] = sum_k A[m,k]*W[o,k] + bias.  SWAPPED mfma => D reg-dim = W-cols, l16 = token.
// EPI 0: QK of padded QKV (cols 0..1023), 8B stores to Q/K [bh,n,64]
// EPI 2: GELU -> outh bf16 row-major [16384][1536]                     [fc1]
template<int EPI>
__global__ __launch_bounds__(512, 2) void gemm256_kernel(
    const u16* __restrict__ A, const u16* __restrict__ W,
    const float* __restrict__ bias, u16* __restrict__ outh, int K) {
  __shared__ u16 sA[2][16384], sB[2][16384];  // 256x64 bf16 each, double buffered (128 KiB)
  const int m0 = blockIdx.x * 256, n0 = blockIdx.y * 256;
  const int tid = threadIdx.x;
  const int wv = tid >> 6, lane = tid & 63;
  const int wm = (wv >> 2) * 128, wn = (wv & 3) * 64;
  const int l16 = lane & 15, lg = lane >> 4;
  const int ksw = (l16 & 7) << 4;            // read-side swizzle XOR (byte units)

  f32x4 acc[8][4];
#pragma unroll
  for (int i = 0; i < 8; ++i)
#pragma unroll
    for (int jj = 0; jj < 4; ++jj) acc[i][jj] = f32x4{0.f, 0.f, 0.f, 0.f};

  const int nk = K >> 6;
  auto stage = [&](int buf, int kt) {
    const u16* Ab = A + (size_t)m0 * K + kt * 64;
    const u16* Wb = W + (size_t)n0 * K + kt * 64;
#pragma unroll
    for (int j = 0; j < 4; ++j) {
      int cb = j * 512 + wv * 64;             // wave-uniform chunk base
      int c = cb + lane;
      int row = c >> 3, sl = (c & 7) ^ (row & 7);   // inverse swizzle on SOURCE
      async16(Ab + (size_t)row * K + sl * 8, &sA[buf][cb * 8]);
      async16(Wb + (size_t)row * K + sl * 8, &sB[buf][cb * 8]);
    }
  };
  stage(0, 0);
  int buf = 0;
  for (int kt = 0; kt < nk; ++kt) {
    asm volatile("s_waitcnt vmcnt(0)" ::: "memory");
    __builtin_amdgcn_s_barrier();
    if (kt + 1 < nk) stage(buf ^ 1, kt + 1);
#pragma unroll
    for (int ks = 0; ks < 2; ++ks) {
      bf16x8 av[8], bv[4];
#pragma unroll
      for (int f = 0; f < 4; ++f) {
        int rb = wn + f * 16 + l16;
        bv[f] = *(const bf16x8*)((const char*)&sB[buf][0] + rb * 128 + ((ks * 64 + lg * 16) ^ ksw));
      }
#pragma unroll
      for (int f = 0; f < 8; ++f) {
        int ra = wm + f * 16 + l16;
        av[f] = *(const bf16x8*)((const char*)&sA[buf][0] + ra * 128 + ((ks * 64 + lg * 16) ^ ksw));
      }
      __builtin_amdgcn_s_setprio(1);
#pragma unroll
      for (int mf = 0; mf < 8; ++mf)
#pragma unroll
        for (int nf = 0; nf < 4; ++nf)
          acc[mf][nf] = __builtin_amdgcn_mfma_f32_16x16x32_bf16(bv[nf], av[mf], acc[mf][nf], 0, 0, 0);
      __builtin_amdgcn_s_setprio(0);
    }
    buf ^= 1;
  }

  // epilogue: swapped C/D: reg-dim = W cols (4 consecutive), lane l16 = token
#pragma unroll
  for (int mf = 0; mf < 8; ++mf) {
    const int token = m0 + wm + mf * 16 + l16;
    const int b = token >> 10, nn = token & 1023;
#pragma unroll
    for (int nf = 0; nf < 4; ++nf) {
      const int col = n0 + wn + nf * 16 + lg * 4;   // +reg rr
      f32x4 v = acc[mf][nf];
      float4 bb = *(const float4*)(bias + col);
      unsigned long long pk = 0;
      if constexpr (EPI == 0) {
#pragma unroll
        for (int rr = 0; rr < 4; ++rr)
          pk |= (unsigned long long)f2bf(v[rr] + ((const float*)&bb)[rr]) << (16 * rr);
        const int which = col >> 9, h = (col >> 6) & 7, d0 = col & 63;
        size_t idx = (size_t)which * QKSZ + (size_t)((b * 8 + h) * 1024 + nn) * 64 + d0;
        *(unsigned long long*)&outh[idx] = pk;
      } else { // EPI 2: GELU, row-major [token][1536]
#pragma unroll
        for (int rr = 0; rr < 4; ++rr)
          pk |= (unsigned long long)f2bf(gelu_f(v[rr] + ((const float*)&bb)[rr])) << (16 * rr);
        *(unsigned long long*)&outh[(size_t)token * 1536 + col] = pk;
      }
    }
  }
}

// ---- 128x128 / BK=64 / 4-wave bf16 GEMM (same pipeline/swizzle), normal orientation ----
// EPI 4: V  of padded QKV (cols 1024..1535), 8B stores to Vt [bh,64,n]
// EPI 1: += resid (x, (B,C,N) read) -> outf (B,C,N) f32                [proj]
// EPI 3: += resid (y1t (B,C,N)) -> outf = d_out (B,C,N) f32            [fc2]
template<int EPI>
__global__ __launch_bounds__(256, 2) void gemm_kernel(
    const u16* __restrict__ A, const u16* __restrict__ W,
    const float* __restrict__ bias, float* __restrict__ outf,
    u16* __restrict__ outh, const float* __restrict__ resid, int K) {
  __shared__ u16 sA[2][8192], sB[2][8192];  // 128x64 bf16 each, double buffered (64 KiB)
  const int m0 = blockIdx.x * 128;
  const int n0 = (EPI == 4 ? 1024 : 0) + blockIdx.y * 128;
  const int wv = threadIdx.x >> 6, lane = threadIdx.x & 63;
  const int wm = (wv >> 1) * 64, wn = (wv & 1) * 64;
  const int l16 = lane & 15, lg = lane >> 4;
  const int ksw = (l16 & 7) << 4;

  f32x4 acc[4][4];
#pragma unroll
  for (int i = 0; i < 4; ++i)
#pragma unroll
    for (int jj = 0; jj < 4; ++jj) acc[i][jj] = f32x4{0.f, 0.f, 0.f, 0.f};

  const int nk = K >> 6;
  auto stage = [&](int buf, int kt) {
    const u16* Ab = A + (size_t)m0 * K + kt * 64;
    const u16* Wb = W + (size_t)n0 * K + kt * 64;
#pragma unroll
    for (int j = 0; j < 4; ++j) {
      int cb = j * 256 + wv * 64;
      int c = cb + lane;
      int row = c >> 3, sl = (c & 7) ^ (row & 7);
      async16(Ab + (size_t)row * K + sl * 8, &sA[buf][cb * 8]);
      async16(Wb + (size_t)row * K + sl * 8, &sB[buf][cb * 8]);
    }
  };
  stage(0, 0);
  int buf = 0;
  for (int kt = 0; kt < nk; ++kt) {
    asm volatile("s_waitcnt vmcnt(0)" ::: "memory");
    __builtin_amdgcn_s_barrier();
    if (kt + 1 < nk) stage(buf ^ 1, kt + 1);
#pragma unroll
    for (int ks = 0; ks < 2; ++ks) {
      bf16x8 av[4], bv[4];
#pragma unroll
      for (int f = 0; f < 4; ++f) {
        int ra = wm + f * 16 + l16, rb = wn + f * 16 + l16;
        av[f] = *(const bf16x8*)((const char*)&sA[buf][0] + ra * 128 + ((ks * 64 + lg * 16) ^ ksw));
        bv[f] = *(const bf16x8*)((const char*)&sB[buf][0] + rb * 128 + ((ks * 64 + lg * 16) ^ ksw));
      }
      __builtin_amdgcn_s_setprio(1);
#pragma unroll
      for (int mf = 0; mf < 4; ++mf)
#pragma unroll
        for (int nf = 0; nf < 4; ++nf)
          acc[mf][nf] = __builtin_amdgcn_mfma_f32_16x16x32_bf16(av[mf], bv[nf], acc[mf][nf], 0, 0, 0);
      __builtin_amdgcn_s_setprio(0);
    }
    buf ^= 1;
  }

  // epilogue: normal C/D: reg-dim = tokens (4 consecutive), lane l16 = W col
#pragma unroll
  for (int mf = 0; mf < 4; ++mf) {
    const int mm = m0 + wm + mf * 16 + lg * 4;      // token base
    const int b = mm >> 10, nn = mm & 1023;
#pragma unroll
    for (int nf = 0; nf < 4; ++nf) {
      const int col = n0 + wn + nf * 16 + l16;
      f32x4 v = acc[mf][nf];
      const float bs = bias[col];
      if constexpr (EPI == 4) {  // V -> Vt [bh][d][n], 4 consecutive n = 8B store
        unsigned long long pk = 0;
#pragma unroll
        for (int rr = 0; rr < 4; ++rr)
          pk |= (unsigned long long)f2bf(v[rr] + bs) << (16 * rr);
        const int h = (col >> 6) & 7, d = col & 63;
        size_t idx = 2ull * QKSZ + (((size_t)((b * 8 + h) * 64 + d)) << 10) + nn;
        *(unsigned long long*)&outh[idx] = pk;
      } else {  // EPI 1 / 3: residual add, (B,C,N) f32, n fast -> float4
        size_t idx = ((size_t)(b * 384 + col) << 10) + nn;
        float4 rr4 = *(const float4*)&resid[idx];
        float4 o{v[0] + bs + rr4.x, v[1] + bs + rr4.y, v[2] + bs + rr4.z, v[3] + bs + rr4.w};
        *(float4*)&outf[idx] = o;
      }
    }
  }
}

// ---- flash attention: Q(scaled) [bh,n,64] x K [bh,n,64] -> softmax -> V^T [bh,64,n] ----
// 1024 blocks = 128 (b,h) x 8 q-tiles of 128 rows. 4 waves, 32 q-rows each. KV tile = 64.
// 2-buffer T3-min pipeline; XOR-swizzled K/V/Q; no online max (logits bounded).
__global__ __launch_bounds__(256, 3) void attn_kernel(
    const u16* __restrict__ Qg, const u16* __restrict__ Kg,
    const u16* __restrict__ Vtg, u16* __restrict__ outp) {
  __shared__ u16 Ks[2][4096];
  __shared__ u16 Vs[2][4096];
  __shared__ u16 QPs[4 * 32 * 72]; // Q staging (8192 u16) then per-wave P tiles (stride 72)
  const int orig = blockIdx.x;
  const int swz = (orig & 7) * 128 + (orig >> 3);   // XCD swizzle: 8 q-tiles of a bh share an XCD
  const int bh = swz >> 3, qt = swz & 7;
  const int w = threadIdx.x >> 6, lane = threadIdx.x & 63;
  const int l16 = lane & 15, lg = lane >> 4;

  const u16* kbase = Kg + (size_t)bh * 1024 * 64;
  const u16* vbase = Vtg + (size_t)bh * 64 * 1024;

  auto stageKV = [&](int buf, int kv) {
#pragma unroll
    for (int i = 0; i < 2; ++i) {
      int cb = (i * 4 + w) * 64;
      int ck = cb + lane;
      int g  = ck ^ ((ck >> 3) & 7);              // inverse swizzle on the SOURCE
      async16(kbase + (size_t)kv * 4096 + g * 8, &Ks[buf][cb * 8]);
      async16(vbase + (size_t)(g >> 3) * 1024 + kv * 64 + (g & 7) * 8, &Vs[buf][cb * 8]);
    }
  };

  { // stage Q tile 128x64 (contiguous in global), swizzled
    const u16* src = Qg + (size_t)(bh * 1024 + qt * 128) * 64;
#pragma unroll
    for (int i = 0; i < 4; ++i) {
      int cb = (i * 4 + w) * 64;
      int ck = cb + lane;
      int g  = ck ^ ((ck >> 3) & 7);
      async16(src + g * 8, &QPs[cb * 8]);
    }
  }
  stageKV(0, 0);
  asm volatile("s_waitcnt vmcnt(0)" ::: "memory");
  __builtin_amdgcn_s_barrier();

  bf16x8 qf[2][2];
#pragma unroll
  for (int mf = 0; mf < 2; ++mf)
#pragma unroll
    for (int ks = 0; ks < 2; ++ks)
      qf[mf][ks] = *lds_swz(QPs, w * 32 + mf * 16 + l16, ks * 64 + lg * 16);
  asm volatile("s_waitcnt lgkmcnt(0)" ::: "memory");
  __builtin_amdgcn_s_barrier();  // all Q reads done before QPs is reused for P

  float lr[2][4];
  f32x4 acco[2][4];
#pragma unroll
  for (int mf = 0; mf < 2; ++mf) {
#pragma unroll
    for (int r = 0; r < 4; ++r) lr[mf][r] = 0.f;
#pragma unroll
    for (int df = 0; df < 4; ++df) acco[mf][df] = f32x4{0.f, 0.f, 0.f, 0.f};
  }
  u16* Pw = &QPs[w * 32 * 72];

  auto compute = [&](int buf) {
    f32x4 accs[2][4];
#pragma unroll
    for (int mf = 0; mf < 2; ++mf)
#pragma unroll
      for (int nf = 0; nf < 4; ++nf) accs[mf][nf] = f32x4{0.f, 0.f, 0.f, 0.f};
    __builtin_amdgcn_s_setprio(1);
#pragma unroll
    for (int nf = 0; nf < 4; ++nf) {
      bf16x8 k0 = *lds_swz(Ks[buf], nf * 16 + l16, lg * 16);
      bf16x8 k1 = *lds_swz(Ks[buf], nf * 16 + l16, 64 + lg * 16);
#pragma unroll
      for (int mf = 0; mf < 2; ++mf) {
        accs[mf][nf] = __builtin_amdgcn_mfma_f32_16x16x32_bf16(qf[mf][0], k0, accs[mf][nf], 0, 0, 0);
        accs[mf][nf] = __builtin_amdgcn_mfma_f32_16x16x32_bf16(qf[mf][1], k1, accs[mf][nf], 0, 0, 0);
      }
    }
    __builtin_amdgcn_s_setprio(0);
    // softmax numerator: p = exp(S) (scale pre-folded into Q, logits bounded)
#pragma unroll
    for (int mf = 0; mf < 2; ++mf)
#pragma unroll
      for (int r = 0; r < 4; ++r) {
        float s0 = __expf(accs[mf][0][r]);
        float s1 = __expf(accs[mf][1][r]);
        float s2 = __expf(accs[mf][2][r]);
        float s3 = __expf(accs[mf][3][r]);
        accs[mf][0][r] = s0; accs[mf][1][r] = s1;
        accs[mf][2][r] = s2; accs[mf][3][r] = s3;
        lr[mf][r] += s0 + s1 + s2 + s3;          // in-lane partial; cross-lane reduce at end
      }
    // write P (C-layout) to LDS, re-read in A-layout for PV
#pragma unroll
    for (int mf = 0; mf < 2; ++mf)
#pragma unroll
      for (int nf = 0; nf < 4; ++nf)
#pragma unroll
        for (int r = 0; r < 4; ++r)
          Pw[(mf * 16 + lg * 4 + r) * 72 + nf * 16 + l16] = f2bf(accs[mf][nf][r]);
    asm volatile("s_waitcnt lgkmcnt(0)" ::: "memory");
#pragma unroll
    for (int ks = 0; ks < 2; ++ks) {
      bf16x8 pa[2], vf[4];
#pragma unroll
      for (int mf = 0; mf < 2; ++mf)
        pa[mf] = *(const bf16x8*)&Pw[(mf * 16 + l16) * 72 + ks * 32 + lg * 8];
#pragma unroll
      for (int df = 0; df < 4; ++df)
        vf[df] = *lds_swz(Vs[buf], df * 16 + l16, ks * 64 + lg * 16);
      __builtin_amdgcn_s_setprio(1);
#pragma unroll
      for (int mf = 0; mf < 2; ++mf)
#pragma unroll
        for (int df = 0; df < 4; ++df)
          acco[mf][df] = __builtin_amdgcn_mfma_f32_16x16x32_bf16(pa[mf], vf[df], acco[mf][df], 0, 0, 0);
      __builtin_amdgcn_s_setprio(0);
    }
  };

  int buf = 0;
  for (int kv = 0; kv < 16; ++kv) {
    if (kv + 1 < 16) stageKV(buf ^ 1, kv + 1);  // loads fly over this tile's compute
    compute(buf);
    asm volatile("s_waitcnt vmcnt(0)" ::: "memory");
    __builtin_amdgcn_s_barrier();                // next KV landed for ALL waves
    buf ^= 1;
  }

  // epilogue: reduce l across the 16 cols, then out[(b*1024+token)*384 + h*48 + d], d < 48
  const int b = bh >> 3, h = bh & 7;
#pragma unroll
  for (int mf = 0; mf < 2; ++mf)
#pragma unroll
    for (int r = 0; r < 4; ++r) {
      float t = lr[mf][r];
      t += __shfl_xor(t, 1); t += __shfl_xor(t, 2);
      t += __shfl_xor(t, 4); t += __shfl_xor(t, 8);
      float inv = 1.f / t;
      int token = qt * 128 + w * 32 + mf * 16 + lg * 4 + r;
      size_t rowb = (size_t)(b * 1024 + token) * 384 + h * 48;
#pragma unroll
      for (int df = 0; df < 3; ++df)
        outp[rowb + df * 16 + l16] = f2bf(acco[mf][df][r] * inv);
    }
}

// ---- workspace layout (bytes) ----
constexpr size_t OFF_WQKVP = 0;          // 1536*384*2   = 1179648
constexpr size_t OFF_BIASP = 1179648;    // 1536*4      -> 1185792
constexpr size_t OFF_WPROJ = 1185792;    // 384*384*2   -> 1480704
constexpr size_t OFF_WFC1  = 1480704;    // 1536*384*2  -> 2660352
constexpr size_t OFF_WFC2  = 2660352;    // 384*1536*2  -> 3840000
constexpr size_t OFF_H     = 3840000;    // 16384*384*2 -> 16422912 (h1, later h2)
constexpr size_t OFF_QKV   = 16422912;   // 3*QKSZ*2    -> 66754560 (later f1)
constexpr size_t OFF_AO    = 66754560;   // 16384*384*2 -> 79337472
constexpr size_t OFF_Y1T   = 79337472;   // 16384*384*4 -> 104503296 total

extern "C" void kernel_launch(void* const* d_in, const int* in_sizes, int n_in,
                              void* d_out, int out_size, void* d_ws, size_t ws_size,
                              hipStream_t stream) {
  (void)in_sizes; (void)n_in; (void)out_size; (void)ws_size;
  const float* x     = (const float*)d_in[0];
  const float* ln1w  = (const float*)d_in[1];
  const float* ln1b  = (const float*)d_in[2];
  const float* qkvw  = (const float*)d_in[3];
  const float* qkvbi = (const float*)d_in[4];
  const float* projw = (const float*)d_in[5];
  const float* projb = (const float*)d_in[6];
  const float* ln2w  = (const float*)d_in[7];
  const float* ln2b  = (const float*)d_in[8];
  const float* fc1w  = (const float*)d_in[9];
  const float* fc1b  = (const float*)d_in[10];
  const float* fc2w  = (const float*)d_in[11];
  const float* fc2b  = (const float*)d_in[12];

  char* ws = (char*)d_ws;
  u16*   wqkvp = (u16*)(ws + OFF_WQKVP);
  float* biasp = (float*)(ws + OFF_BIASP);
  u16*   wproj = (u16*)(ws + OFF_WPROJ);
  u16*   wfc1  = (u16*)(ws + OFF_WFC1);
  u16*   wfc2  = (u16*)(ws + OFF_WFC2);
  u16*   h1    = (u16*)(ws + OFF_H);     // also h2
  u16*   qkvs  = (u16*)(ws + OFF_QKV);   // Q | K | Vt ; later f1
  u16*   f1    = qkvs;
  u16*   ao    = (u16*)(ws + OFF_AO);
  float* y1t   = (float*)(ws + OFF_Y1T);

  cvt_kernel<<<1874, 256, 0, stream>>>(qkvw, qkvbi, projw, fc1w, fc2w,
                                       wqkvp, biasp, wproj, wfc1, wfc2);

  dim3 lngrid(32, 16);
  ln_kernel<<<lngrid, 256, 0, stream>>>(x, ln1w, ln1b, h1);

  // QKV: QK via 256^2 swapped kernel (grid 256 blocks = 1/CU); V via 128^2 (512 blocks)
  gemm256_kernel<0><<<dim3(64, 4), 512, 0, stream>>>(h1, wqkvp, biasp, qkvs, 384);
  gemm_kernel<4><<<dim3(128, 4), 256, 0, stream>>>(h1, wqkvp, biasp, nullptr, qkvs, nullptr, 384);

  attn_kernel<<<dim3(1024), 256, 0, stream>>>(qkvs, qkvs + QKSZ, qkvs + 2 * QKSZ, ao);

  gemm_kernel<1><<<dim3(128, 3), 256, 0, stream>>>(ao, wproj, projb, y1t, nullptr, x, 384);

  ln_kernel<<<lngrid, 256, 0, stream>>>(y1t, ln2w, ln2b, h1 /*h2*/);

  gemm256_kernel<2><<<dim3(64, 6), 512, 0, stream>>>(h1, wfc1, fc1b, f1, 384);

  gemm_kernel<3><<<dim3(128, 3), 256, 0, stream>>>(f1, wfc2, fc2b, (float*)d_out, nullptr, y1t, 1536);
}

// Round 5
// 315.026 us; speedup vs baseline: 1.0187x; 1.0083x over previous
//
#include <hip/hip_runtime.h>

typedef unsigned short u16;
using bf16x8 = __attribute__((ext_vector_type(8))) short;
using f32x4  = __attribute__((ext_vector_type(4))) float;
using f32x16 = __attribute__((ext_vector_type(16))) float;

#define DEV __device__ __forceinline__

// ---- constants ----
// B=16, C=384, H=W=32 -> N=1024 tokens per batch, 16384 total. heads=8, hd=48 (padded to 64).
constexpr int    NTOK = 16384;
constexpr size_t QKSZ = (size_t)16 * 8 * 1024 * 64; // elements per Q / K / Vt buffer (8388608)
constexpr float  ATTN_SCALE = 0.14433756729740645f; // 48^-0.5 (folded into Q weights at cvt)

DEV u16 f2bf(float x) {                 // f32 -> bf16 RNE
  unsigned int u = __float_as_uint(x);
  u += 0x7fffu + ((u >> 16) & 1u);
  return (u16)(u >> 16);
}

DEV void async16(const u16* g, u16* l) { // global -> LDS direct, 16B per lane (dest wave-uniform)
  __builtin_amdgcn_global_load_lds(
      (const __attribute__((address_space(1))) unsigned int*)g,
      (__attribute__((address_space(3))) unsigned int*)l, 16, 0, 0);
}

// swizzled LDS read for attn [rows][64 bf16] tiles (128B row): byte ^= (row&7)<<4
DEV const bf16x8* lds_swz(const u16* base, int row, int bytecol) {
  int byte = row * 128 + bytecol;
  byte ^= (row & 7) << 4;
  return (const bf16x8*)((const char*)base + byte);
}

DEV f32x16 zero16() {
  f32x16 z;
#pragma unroll
  for (int i = 0; i < 16; ++i) z[i] = 0.f;
  return z;
}

// fast exact-enough GELU: tanh form via one exp; |err| < ~3.5e-4 abs
DEV float gelu_f(float x) {
  float y = 0.7978845608028654f * (x + 0.044715f * x * x * x);
  float e = __expf(2.f * y);
  float t = 1.f - 2.f / (e + 1.f);
  return 0.5f * x * (1.f + t);
}

// XCD-grouped block remap: same-A-panel blocks land on one XCD (L2-resident A stripe).
// Requires gridDim.x % 8 == 0. Returns (bx, by).
DEV void xcd_remap(int& bx, int& by) {
  int p = blockIdx.x + gridDim.x * blockIdx.y;
  int nxs = gridDim.x >> 3;
  int xcd = p & 7, q = p >> 3;
  bx = xcd * nxs + q % nxs;
  by = q / nxs;
}

// ---- weight convert + QKV padding (d 48..63 zero, ATTN_SCALE folded into Q rows/bias) ----
__global__ void cvt_kernel(const float* __restrict__ qkvw, const float* __restrict__ qkvb,
                           const float* __restrict__ projw, const float* __restrict__ fc1w,
                           const float* __restrict__ fc2w,
                           u16* __restrict__ wqkvp, float* __restrict__ biasp,
                           u16* __restrict__ wproj, u16* __restrict__ wfc1,
                           u16* __restrict__ wfc2) {
  int i = blockIdx.x * 256 + threadIdx.x;  // quad index
  if (i < 147456) {                        // padded qkv weight [1536][384]
    int p = i / 96, q = (i - p * 96) * 4;
    int which = p >> 9, h = (p >> 6) & 7, d = p & 63;
    ushort4 o{0, 0, 0, 0};
    if (d < 48) {
      float sc = which ? 1.f : ATTN_SCALE;
      float4 v = *(const float4*)(qkvw + (size_t)(which * 384 + h * 48 + d) * 384 + q);
      o = ushort4{f2bf(v.x * sc), f2bf(v.y * sc), f2bf(v.z * sc), f2bf(v.w * sc)};
    }
    *(ushort4*)(wqkvp + (size_t)p * 384 + q) = o;
  } else if (i < 479232) {                 // plain converts
    const float* s; u16* d; int off;
    if (i < 184320)      { s = projw; d = wproj; off = i - 147456; }
    else if (i < 331776) { s = fc1w;  d = wfc1;  off = i - 184320; }
    else                 { s = fc2w;  d = wfc2;  off = i - 331776; }
    float4 v = *(const float4*)(s + (size_t)off * 4);
    *(ushort4*)(d + (size_t)off * 4) = ushort4{f2bf(v.x), f2bf(v.y), f2bf(v.z), f2bf(v.w)};
  } else if (i < 479616) {                 // padded qkv bias [1536] f32
    int qi = (i - 479232) * 4;
    float4 o;
    float* op = (float*)&o;
#pragma unroll
    for (int r = 0; r < 4; ++r) {
      int p = qi + r, which = p >> 9, h = (p >> 6) & 7, d = p & 63;
      op[r] = (d < 48) ? qkvb[which * 384 + h * 48 + d] * (which ? 1.f : ATTN_SCALE) : 0.f;
    }
    *(float4*)(biasp + qi) = o;
  }
}

// ---- LayerNorm over C=384 with transpose: in (B, 384, 1024) f32 -> out (B*1024, 384) bf16 ----
__global__ __launch_bounds__(256) void ln_kernel(
    const float* __restrict__ in, const float* __restrict__ gw,
    const float* __restrict__ gb, u16* __restrict__ out) {
  __shared__ float tile[32][385];
  __shared__ float mu_s[32], rs_s[32];
  const int b = blockIdx.y;
  const int n0 = blockIdx.x * 32;
  const int t = threadIdx.x;
  const int j = t & 31, cb = t >> 5;
  const float* src = in + (size_t)b * 384 * 1024 + n0;
  for (int k = 0; k < 48; ++k) {
    int c = k * 8 + cb;
    tile[j][c] = src[(size_t)c * 1024 + j];   // coalesced along n
  }
  __syncthreads();
  const int jt = t >> 3, r = t & 7;           // 8 threads per token
  float s = 0.f, ss = 0.f;
  for (int c = r; c < 384; c += 8) { float v = tile[jt][c]; s += v; ss += v * v; }
  s += __shfl_xor(s, 1); ss += __shfl_xor(ss, 1);
  s += __shfl_xor(s, 2); ss += __shfl_xor(ss, 2);
  s += __shfl_xor(s, 4); ss += __shfl_xor(ss, 4);
  const float mean = s * (1.f / 384.f);
  const float var  = ss * (1.f / 384.f) - mean * mean;  // ddof=0
  if (r == 0) { mu_s[jt] = mean; rs_s[jt] = rsqrtf(var + 1e-5f); }
  __syncthreads();
  for (int q = t; q < 3072; q += 256) {       // 32 tokens x 96 ushort4 quads
    int tok = q / 96, c4 = (q - tok * 96) * 4;
    float m = mu_s[tok], rv = rs_s[tok];
    float4 wv = *(const float4*)(gw + c4);
    float4 bv = *(const float4*)(gb + c4);
    u16* dst = out + (size_t)(b * 1024 + n0 + tok) * 384 + c4;
    ushort4 o{f2bf((tile[tok][c4 + 0] - m) * rv * wv.x + bv.x),
              f2bf((tile[tok][c4 + 1] - m) * rv * wv.y + bv.y),
              f2bf((tile[tok][c4 + 2] - m) * rv * wv.z + bv.z),
              f2bf((tile[tok][c4 + 3] - m) * rv * wv.w + bv.w)};
    *(ushort4*)dst = o;
  }
}

// ---- 256x256 / BK=32 / 8-wave bf16 GEMM (2 blocks/CU, XCD-grouped) ----
// out[m,o] = sum_k A[m,k]*W[o,k] + bias.  SWAPPED mfma => D reg-dim = W-cols, l16 = token.
// EPI 0: QK of padded QKV (cols 0..1023), 8B stores to Q/K [bh,n,64]
// EPI 2: GELU -> outh bf16 row-major [16384][1536]                     [fc1]
template<int EPI>
__global__ __launch_bounds__(512, 2) void gemm256_kernel(
    const u16* __restrict__ A, const u16* __restrict__ W,
    const float* __restrict__ bias, u16* __restrict__ outh, int K) {
  __shared__ u16 sA[2][8192], sB[2][8192];  // 256x32 bf16 each, double buffered (64 KiB)
  int bx, by; xcd_remap(bx, by);
  const int m0 = bx * 256, n0 = by * 256;
  const int tid = threadIdx.x;
  const int wv = tid >> 6, lane = tid & 63;
  const int wm = (wv >> 2) * 128, wn = (wv & 3) * 64;
  const int l16 = lane & 15, lg = lane >> 4;
  const int rsw = ((lg ^ (l16 & 3)) << 4);   // read-side swizzle (64B rows, 4 slots)

  f32x4 acc[8][4];
#pragma unroll
  for (int i = 0; i < 8; ++i)
#pragma unroll
    for (int jj = 0; jj < 4; ++jj) acc[i][jj] = f32x4{0.f, 0.f, 0.f, 0.f};

  const int nk = K >> 5;
  auto stage = [&](int buf, int kt) {
    const u16* Ab = A + (size_t)m0 * K + kt * 32;
    const u16* Wb = W + (size_t)n0 * K + kt * 32;
#pragma unroll
    for (int j = 0; j < 2; ++j) {
      int cb = j * 512 + wv * 64;             // wave-uniform chunk base
      int c = cb + lane;
      int row = c >> 2, sl = (c & 3) ^ (row & 3);   // inverse swizzle on SOURCE
      async16(Ab + (size_t)row * K + sl * 8, &sA[buf][cb * 8]);
      async16(Wb + (size_t)row * K + sl * 8, &sB[buf][cb * 8]);
    }
  };
  stage(0, 0);
  int buf = 0;
  for (int kt = 0; kt < nk; ++kt) {
    asm volatile("s_waitcnt vmcnt(0)" ::: "memory");
    __builtin_amdgcn_s_barrier();
    if (kt + 1 < nk) stage(buf ^ 1, kt + 1);
    bf16x8 av[8], bv[4];
#pragma unroll
    for (int f = 0; f < 4; ++f)
      bv[f] = *(const bf16x8*)((const char*)&sB[buf][0] + (wn + f * 16 + l16) * 64 + rsw);
#pragma unroll
    for (int f = 0; f < 8; ++f)
      av[f] = *(const bf16x8*)((const char*)&sA[buf][0] + (wm + f * 16 + l16) * 64 + rsw);
    __builtin_amdgcn_s_setprio(1);
#pragma unroll
    for (int mf = 0; mf < 8; ++mf)
#pragma unroll
      for (int nf = 0; nf < 4; ++nf)
        acc[mf][nf] = __builtin_amdgcn_mfma_f32_16x16x32_bf16(bv[nf], av[mf], acc[mf][nf], 0, 0, 0);
    __builtin_amdgcn_s_setprio(0);
    buf ^= 1;
  }

  // epilogue: swapped C/D: reg-dim = W cols (4 consecutive), lane l16 = token
#pragma unroll
  for (int mf = 0; mf < 8; ++mf) {
    const int token = m0 + wm + mf * 16 + l16;
    const int b = token >> 10, nn = token & 1023;
#pragma unroll
    for (int nf = 0; nf < 4; ++nf) {
      const int col = n0 + wn + nf * 16 + lg * 4;   // +reg rr
      f32x4 v = acc[mf][nf];
      float4 bb = *(const float4*)(bias + col);
      unsigned long long pk = 0;
      if constexpr (EPI == 0) {
#pragma unroll
        for (int rr = 0; rr < 4; ++rr)
          pk |= (unsigned long long)f2bf(v[rr] + ((const float*)&bb)[rr]) << (16 * rr);
        const int which = col >> 9, h = (col >> 6) & 7, d0 = col & 63;
        size_t idx = (size_t)which * QKSZ + (size_t)((b * 8 + h) * 1024 + nn) * 64 + d0;
        *(unsigned long long*)&outh[idx] = pk;
      } else { // EPI 2: GELU, row-major [token][1536]
#pragma unroll
        for (int rr = 0; rr < 4; ++rr)
          pk |= (unsigned long long)f2bf(gelu_f(v[rr] + ((const float*)&bb)[rr])) << (16 * rr);
        *(unsigned long long*)&outh[(size_t)token * 1536 + col] = pk;
      }
    }
  }
}

// ---- 128x128 / BK=64 / 4-wave bf16 GEMM (XCD-grouped), normal orientation ----
// EPI 4: V  of padded QKV (cols 1024..1535), 8B stores to Vt [bh,64,n]
// EPI 1: += resid (x, (B,C,N) read) -> outf (B,C,N) f32                [proj]
// EPI 3: += resid (y1t (B,C,N)) -> outf = d_out (B,C,N) f32            [fc2]
template<int EPI>
__global__ __launch_bounds__(256, 2) void gemm_kernel(
    const u16* __restrict__ A, const u16* __restrict__ W,
    const float* __restrict__ bias, float* __restrict__ outf,
    u16* __restrict__ outh, const float* __restrict__ resid, int K) {
  __shared__ u16 sA[2][8192], sB[2][8192];  // 128x64 bf16 each, double buffered (64 KiB)
  int bx, by; xcd_remap(bx, by);
  const int m0 = bx * 128;
  const int n0 = (EPI == 4 ? 1024 : 0) + by * 128;
  const int wv = threadIdx.x >> 6, lane = threadIdx.x & 63;
  const int wm = (wv >> 1) * 64, wn = (wv & 1) * 64;
  const int l16 = lane & 15, lg = lane >> 4;
  const int ksw = (l16 & 7) << 4;

  f32x4 acc[4][4];
#pragma unroll
  for (int i = 0; i < 4; ++i)
#pragma unroll
    for (int jj = 0; jj < 4; ++jj) acc[i][jj] = f32x4{0.f, 0.f, 0.f, 0.f};

  const int nk = K >> 6;
  auto stage = [&](int buf, int kt) {
    const u16* Ab = A + (size_t)m0 * K + kt * 64;
    const u16* Wb = W + (size_t)n0 * K + kt * 64;
#pragma unroll
    for (int j = 0; j < 4; ++j) {
      int cb = j * 256 + wv * 64;
      int c = cb + lane;
      int row = c >> 3, sl = (c & 7) ^ (row & 7);
      async16(Ab + (size_t)row * K + sl * 8, &sA[buf][cb * 8]);
      async16(Wb + (size_t)row * K + sl * 8, &sB[buf][cb * 8]);
    }
  };
  stage(0, 0);
  int buf = 0;
  for (int kt = 0; kt < nk; ++kt) {
    asm volatile("s_waitcnt vmcnt(0)" ::: "memory");
    __builtin_amdgcn_s_barrier();
    if (kt + 1 < nk) stage(buf ^ 1, kt + 1);
#pragma unroll
    for (int ks = 0; ks < 2; ++ks) {
      bf16x8 av[4], bv[4];
#pragma unroll
      for (int f = 0; f < 4; ++f) {
        int ra = wm + f * 16 + l16, rb = wn + f * 16 + l16;
        av[f] = *(const bf16x8*)((const char*)&sA[buf][0] + ra * 128 + ((ks * 64 + lg * 16) ^ ksw));
        bv[f] = *(const bf16x8*)((const char*)&sB[buf][0] + rb * 128 + ((ks * 64 + lg * 16) ^ ksw));
      }
      __builtin_amdgcn_s_setprio(1);
#pragma unroll
      for (int mf = 0; mf < 4; ++mf)
#pragma unroll
        for (int nf = 0; nf < 4; ++nf)
          acc[mf][nf] = __builtin_amdgcn_mfma_f32_16x16x32_bf16(av[mf], bv[nf], acc[mf][nf], 0, 0, 0);
      __builtin_amdgcn_s_setprio(0);
    }
    buf ^= 1;
  }

  // epilogue: normal C/D: reg-dim = tokens (4 consecutive), lane l16 = W col
#pragma unroll
  for (int mf = 0; mf < 4; ++mf) {
    const int mm = m0 + wm + mf * 16 + lg * 4;      // token base
    const int b = mm >> 10, nn = mm & 1023;
#pragma unroll
    for (int nf = 0; nf < 4; ++nf) {
      const int col = n0 + wn + nf * 16 + l16;
      f32x4 v = acc[mf][nf];
      const float bs = bias[col];
      if constexpr (EPI == 4) {  // V -> Vt [bh][d][n], 4 consecutive n = 8B store
        unsigned long long pk = 0;
#pragma unroll
        for (int rr = 0; rr < 4; ++rr)
          pk |= (unsigned long long)f2bf(v[rr] + bs) << (16 * rr);
        const int h = (col >> 6) & 7, d = col & 63;
        size_t idx = 2ull * QKSZ + (((size_t)((b * 8 + h) * 64 + d)) << 10) + nn;
        *(unsigned long long*)&outh[idx] = pk;
      } else {  // EPI 1 / 3: residual add, (B,C,N) f32, n fast -> float4
        size_t idx = ((size_t)(b * 384 + col) << 10) + nn;
        float4 rr4 = *(const float4*)&resid[idx];
        float4 o{v[0] + bs + rr4.x, v[1] + bs + rr4.y, v[2] + bs + rr4.z, v[3] + bs + rr4.w};
        *(float4*)&outf[idx] = o;
      }
    }
  }
}

// ---- flash attention, 32x32 MFMA swapped-QK in-register softmax (T12 pattern) ----
// 1024 blocks = 128 (b,h) x 8 q-tiles of 128 rows. 4 waves, 32 q-rows each. KV tile = 64.
// S^T = mfma32(K, Q): lane holds full P-row (q = lane&31) -> in-lane softmax, no LDS P.
// P -> bf16 A-frags via v_cvt_pk_bf16_f32 + v_permlane32_swap_b32.
__global__ __launch_bounds__(256, 3) void attn_kernel(
    const u16* __restrict__ Qg, const u16* __restrict__ Kg,
    const u16* __restrict__ Vtg, u16* __restrict__ outp) {
  __shared__ u16 Ks[2][4096];
  __shared__ u16 Vs[2][4096];
  __shared__ u16 Qs[8192];                          // 128 x 64
  const int orig = blockIdx.x;
  const int swz = (orig & 7) * 128 + (orig >> 3);   // XCD swizzle: 8 q-tiles of a bh share an XCD
  const int bh = swz >> 3, qt = swz & 7;
  const int w = threadIdx.x >> 6, lane = threadIdx.x & 63;
  const int l31 = lane & 31, hi = lane >> 5;

  const u16* kbase = Kg + (size_t)bh * 65536;
  const u16* vbase = Vtg + (size_t)bh * 65536;

  auto stageKV = [&](int buf, int kv) {
#pragma unroll
    for (int i = 0; i < 2; ++i) {
      int cb = (i * 4 + w) * 64;
      int ck = cb + lane;
      int g  = ck ^ ((ck >> 3) & 7);              // inverse swizzle on the SOURCE
      async16(kbase + (size_t)kv * 4096 + g * 8, &Ks[buf][cb * 8]);
      async16(vbase + (size_t)(g >> 3) * 1024 + kv * 64 + (g & 7) * 8, &Vs[buf][cb * 8]);
    }
  };

  { // stage Q tile 128x64 (contiguous in global), swizzled
    const u16* src = Qg + (size_t)(bh * 1024 + qt * 128) * 64;
#pragma unroll
    for (int i = 0; i < 4; ++i) {
      int cb = (i * 4 + w) * 64;
      int ck = cb + lane;
      int g  = ck ^ ((ck >> 3) & 7);
      async16(src + g * 8, &Qs[cb * 8]);
    }
  }
  stageKV(0, 0);
  asm volatile("s_waitcnt vmcnt(0)" ::: "memory");
  __builtin_amdgcn_s_barrier();

  // Q fragments (B-operand): qf[ds] = Q[q = w*32+l31][d = 16ds+8hi .. +7]
  bf16x8 qf[4];
#pragma unroll
  for (int ds = 0; ds < 4; ++ds)
    qf[ds] = *lds_swz(Qs, w * 32 + l31, ds * 32 + hi * 16);

  f32x16 out0 = zero16(), out1 = zero16();
  float ls0 = 0.f, ls1 = 0.f;

  int buf = 0;
  for (int kv = 0; kv < 16; ++kv) {
    if (kv + 1 < 16) stageKV(buf ^ 1, kv + 1);    // loads fly over this tile's compute

    // --- QK^T (swapped): sacc[kvf] = S^T for kv rows kvf*32..+31, col q = l31 ---
    f32x16 sacc0 = zero16(), sacc1 = zero16();
    __builtin_amdgcn_s_setprio(1);
#pragma unroll
    for (int ds = 0; ds < 4; ++ds) {
      bf16x8 kf0 = *lds_swz(Ks[buf], l31,      ds * 32 + hi * 16);
      bf16x8 kf1 = *lds_swz(Ks[buf], 32 + l31, ds * 32 + hi * 16);
      sacc0 = __builtin_amdgcn_mfma_f32_32x32x16_bf16(kf0, qf[ds], sacc0, 0, 0, 0);
      sacc1 = __builtin_amdgcn_mfma_f32_32x32x16_bf16(kf1, qf[ds], sacc1, 0, 0, 0);
    }
    __builtin_amdgcn_s_setprio(0);

    // --- softmax numerator in-lane: p = exp(S); pack pairs to bf16 ---
    unsigned int c0[8], c1[8];
#pragma unroll
    for (int i = 0; i < 8; ++i) {
      float a = __expf(sacc0[2 * i]), b = __expf(sacc0[2 * i + 1]);
      ls0 += a + b;
      unsigned int pk;
      asm("v_cvt_pk_bf16_f32 %0, %1, %2" : "=v"(pk) : "v"(a), "v"(b));
      c0[i] = pk;
    }
#pragma unroll
    for (int i = 0; i < 8; ++i) {
      float a = __expf(sacc1[2 * i]), b = __expf(sacc1[2 * i + 1]);
      ls1 += a + b;
      unsigned int pk;
      asm("v_cvt_pk_bf16_f32 %0, %1, %2" : "=v"(pk) : "v"(a), "v"(b));
      c1[i] = pk;
    }

    // --- PV: A-frag assembly via permlane32_swap, B = Vt rows (d on l31) ---
#pragma unroll
    for (int m = 0; m < 4; ++m) {
      unsigned int a0 = (m < 2) ? c0[(m & 1) * 4 + 0] : c1[(m & 1) * 4 + 0];
      unsigned int b0 = (m < 2) ? c0[(m & 1) * 4 + 2] : c1[(m & 1) * 4 + 2];
      unsigned int a1 = (m < 2) ? c0[(m & 1) * 4 + 1] : c1[(m & 1) * 4 + 1];
      unsigned int b1 = (m < 2) ? c0[(m & 1) * 4 + 3] : c1[(m & 1) * 4 + 3];
      asm volatile("v_permlane32_swap_b32 %0, %1" : "+v"(a0), "+v"(b0));
      asm volatile("v_permlane32_swap_b32 %0, %1" : "+v"(a1), "+v"(b1));
      union { int4 i; bf16x8 v; } u;
      u.i = int4{(int)a0, (int)a1, (int)b0, (int)b1};
      bf16x8 pa = u.v;
      bf16x8 v0 = *lds_swz(Vs[buf], l31,      m * 32 + hi * 16);
      bf16x8 v1 = *lds_swz(Vs[buf], 32 + l31, m * 32 + hi * 16);
      __builtin_amdgcn_s_setprio(1);
      out0 = __builtin_amdgcn_mfma_f32_32x32x16_bf16(pa, v0, out0, 0, 0, 0);
      out1 = __builtin_amdgcn_mfma_f32_32x32x16_bf16(pa, v1, out1, 0, 0, 0);
      __builtin_amdgcn_s_setprio(0);
    }

    asm volatile("s_waitcnt vmcnt(0)" ::: "memory");
    __builtin_amdgcn_s_barrier();                  // next KV landed for ALL waves
    buf ^= 1;
  }

  // --- epilogue: full row-sum (combine hi halves), normalize, store d<48 ---
  float lf = ls0 + ls1;
  lf += __shfl_xor(lf, 32);
  const int b = bh >> 3, h = bh & 7;
#pragma unroll
  for (int r = 0; r < 16; ++r) {
    const int q = (r & 3) + 8 * (r >> 2) + 4 * hi;     // C/D row pattern
    const float inv = 1.f / __shfl(lf, q);             // lane q holds lsum of q-row
    const int token = qt * 128 + w * 32 + q;
    const size_t rowb = (size_t)(b * 1024 + token) * 384 + h * 48;
    outp[rowb + l31] = f2bf(out0[r] * inv);            // d = l31 (0..31)
    if (l31 < 16) outp[rowb + 32 + l31] = f2bf(out1[r] * inv);  // d = 32..47
  }
}

// ---- workspace layout (bytes) ----
constexpr size_t OFF_WQKVP = 0;          // 1536*384*2   = 1179648
constexpr size_t OFF_BIASP = 1179648;    // 1536*4      -> 1185792
constexpr size_t OFF_WPROJ = 1185792;    // 384*384*2   -> 1480704
constexpr size_t OFF_WFC1  = 1480704;    // 1536*384*2  -> 2660352
constexpr size_t OFF_WFC2  = 2660352;    // 384*1536*2  -> 3840000
constexpr size_t OFF_H     = 3840000;    // 16384*384*2 -> 16422912 (h1, later h2)
constexpr size_t OFF_QKV   = 16422912;   // 3*QKSZ*2    -> 66754560 (later f1)
constexpr size_t OFF_AO    = 66754560;   // 16384*384*2 -> 79337472
constexpr size_t OFF_Y1T   = 79337472;   // 16384*384*4 -> 104503296 total

extern "C" void kernel_launch(void* const* d_in, const int* in_sizes, int n_in,
                              void* d_out, int out_size, void* d_ws, size_t ws_size,
                              hipStream_t stream) {
  (void)in_sizes; (void)n_in; (void)out_size; (void)ws_size;
  const float* x     = (const float*)d_in[0];
  const float* ln1w  = (const float*)d_in[1];
  const float* ln1b  = (const float*)d_in[2];
  const float* qkvw  = (const float*)d_in[3];
  const float* qkvbi = (const float*)d_in[4];
  const float* projw = (const float*)d_in[5];
  const float* projb = (const float*)d_in[6];
  const float* ln2w  = (const float*)d_in[7];
  const float* ln2b  = (const float*)d_in[8];
  const float* fc1w  = (const float*)d_in[9];
  const float* fc1b  = (const float*)d_in[10];
  const float* fc2w  = (const float*)d_in[11];
  const float* fc2b  = (const float*)d_in[12];

  char* ws = (char*)d_ws;
  u16*   wqkvp = (u16*)(ws + OFF_WQKVP);
  float* biasp = (float*)(ws + OFF_BIASP);
  u16*   wproj = (u16*)(ws + OFF_WPROJ);
  u16*   wfc1  = (u16*)(ws + OFF_WFC1);
  u16*   wfc2  = (u16*)(ws + OFF_WFC2);
  u16*   h1    = (u16*)(ws + OFF_H);     // also h2
  u16*   qkvs  = (u16*)(ws + OFF_QKV);   // Q | K | Vt ; later f1
  u16*   f1    = qkvs;
  u16*   ao    = (u16*)(ws + OFF_AO);
  float* y1t   = (float*)(ws + OFF_Y1T);

  cvt_kernel<<<1874, 256, 0, stream>>>(qkvw, qkvbi, projw, fc1w, fc2w,
                                       wqkvp, biasp, wproj, wfc1, wfc2);

  dim3 lngrid(32, 16);
  ln_kernel<<<lngrid, 256, 0, stream>>>(x, ln1w, ln1b, h1);

  // QKV: QK via 256^2 swapped kernel; V via 128^2
  gemm256_kernel<0><<<dim3(64, 4), 512, 0, stream>>>(h1, wqkvp, biasp, qkvs, 384);
  gemm_kernel<4><<<dim3(128, 4), 256, 0, stream>>>(h1, wqkvp, biasp, nullptr, qkvs, nullptr, 384);

  attn_kernel<<<dim3(1024), 256, 0, stream>>>(qkvs, qkvs + QKSZ, qkvs + 2 * QKSZ, ao);

  gemm_kernel<1><<<dim3(128, 3), 256, 0, stream>>>(ao, wproj, projb, y1t, nullptr, x, 384);

  ln_kernel<<<lngrid, 256, 0, stream>>>(y1t, ln2w, ln2b, h1 /*h2*/);

  gemm256_kernel<2><<<dim3(64, 6), 512, 0, stream>>>(h1, wfc1, fc1b, f1, 384);

  gemm_kernel<3><<<dim3(128, 3), 256, 0, stream>>>(f1, wfc2, fc2b, (float*)d_out, nullptr, y1t, 1536);
}

// Round 6
// 314.239 us; speedup vs baseline: 1.0212x; 1.0025x over previous
//
#include <hip/hip_runtime.h>

typedef unsigned short u16;
using bf16x8 = __attribute__((ext_vector_type(8))) short;
using f32x4  = __attribute__((ext_vector_type(4))) float;
using f32x16 = __attribute__((ext_vector_type(16))) float;

#define DEV __device__ __forceinline__

// ---- constants ----
// B=16, C=384, H=W=32 -> N=1024 tokens per batch, 16384 total. heads=8, hd=48 (padded to 64).
constexpr int    NTOK = 16384;
constexpr size_t QKSZ = (size_t)16 * 8 * 1024 * 64; // elements per Q / K / Vt buffer (8388608)
constexpr float  ATTN_SCALE = 0.14433756729740645f; // 48^-0.5 (folded into Q weights at cvt)

DEV u16 f2bf(float x) {                 // f32 -> bf16 RNE
  unsigned int u = __float_as_uint(x);
  u += 0x7fffu + ((u >> 16) & 1u);
  return (u16)(u >> 16);
}

DEV void async16(const u16* g, u16* l) { // global -> LDS direct, 16B per lane (dest wave-uniform)
  __builtin_amdgcn_global_load_lds(
      (const __attribute__((address_space(1))) unsigned int*)g,
      (__attribute__((address_space(3))) unsigned int*)l, 16, 0, 0);
}

// swizzled LDS read for attn [rows][64 bf16] tiles (128B row): byte ^= (row&7)<<4
DEV const bf16x8* lds_swz(const u16* base, int row, int bytecol) {
  int byte = row * 128 + bytecol;
  byte ^= (row & 7) << 4;
  return (const bf16x8*)((const char*)base + byte);
}

DEV f32x16 zero16() {
  f32x16 z;
#pragma unroll
  for (int i = 0; i < 16; ++i) z[i] = 0.f;
  return z;
}

// fast exact-enough GELU: tanh form via one exp; |err| < ~3.5e-4 abs
DEV float gelu_f(float x) {
  float y = 0.7978845608028654f * (x + 0.044715f * x * x * x);
  float e = __expf(2.f * y);
  float t = 1.f - 2.f / (e + 1.f);
  return 0.5f * x * (1.f + t);
}

// XCD-grouped block remap: same-A-panel blocks land on one XCD (L2-resident A stripe).
// Requires gridDim.x % 8 == 0. Returns (bx, by).
DEV void xcd_remap(int& bx, int& by) {
  int p = blockIdx.x + gridDim.x * blockIdx.y;
  int nxs = gridDim.x >> 3;
  int xcd = p & 7, q = p >> 3;
  bx = xcd * nxs + q % nxs;
  by = q / nxs;
}

// ---- weight convert + QKV padding (d 48..63 zero, ATTN_SCALE folded into Q rows/bias) ----
__global__ void cvt_kernel(const float* __restrict__ qkvw, const float* __restrict__ qkvb,
                           const float* __restrict__ projw, const float* __restrict__ fc1w,
                           const float* __restrict__ fc2w,
                           u16* __restrict__ wqkvp, float* __restrict__ biasp,
                           u16* __restrict__ wproj, u16* __restrict__ wfc1,
                           u16* __restrict__ wfc2) {
  int i = blockIdx.x * 256 + threadIdx.x;  // quad index
  if (i < 147456) {                        // padded qkv weight [1536][384]
    int p = i / 96, q = (i - p * 96) * 4;
    int which = p >> 9, h = (p >> 6) & 7, d = p & 63;
    ushort4 o{0, 0, 0, 0};
    if (d < 48) {
      float sc = which ? 1.f : ATTN_SCALE;
      float4 v = *(const float4*)(qkvw + (size_t)(which * 384 + h * 48 + d) * 384 + q);
      o = ushort4{f2bf(v.x * sc), f2bf(v.y * sc), f2bf(v.z * sc), f2bf(v.w * sc)};
    }
    *(ushort4*)(wqkvp + (size_t)p * 384 + q) = o;
  } else if (i < 479232) {                 // plain converts
    const float* s; u16* d; int off;
    if (i < 184320)      { s = projw; d = wproj; off = i - 147456; }
    else if (i < 331776) { s = fc1w;  d = wfc1;  off = i - 184320; }
    else                 { s = fc2w;  d = wfc2;  off = i - 331776; }
    float4 v = *(const float4*)(s + (size_t)off * 4);
    *(ushort4*)(d + (size_t)off * 4) = ushort4{f2bf(v.x), f2bf(v.y), f2bf(v.z), f2bf(v.w)};
  } else if (i < 479616) {                 // padded qkv bias [1536] f32
    int qi = (i - 479232) * 4;
    float4 o;
    float* op = (float*)&o;
#pragma unroll
    for (int r = 0; r < 4; ++r) {
      int p = qi + r, which = p >> 9, h = (p >> 6) & 7, d = p & 63;
      op[r] = (d < 48) ? qkvb[which * 384 + h * 48 + d] * (which ? 1.f : ATTN_SCALE) : 0.f;
    }
    *(float4*)(biasp + qi) = o;
  }
}

// ---- LayerNorm over C=384 with transpose: in (B, 384, 1024) f32 -> out (B*1024, 384) bf16 ----
__global__ __launch_bounds__(256) void ln_kernel(
    const float* __restrict__ in, const float* __restrict__ gw,
    const float* __restrict__ gb, u16* __restrict__ out) {
  __shared__ float tile[32][385];
  __shared__ float mu_s[32], rs_s[32];
  const int b = blockIdx.y;
  const int n0 = blockIdx.x * 32;
  const int t = threadIdx.x;
  const int j = t & 31, cb = t >> 5;
  const float* src = in + (size_t)b * 384 * 1024 + n0;
  for (int k = 0; k < 48; ++k) {
    int c = k * 8 + cb;
    tile[j][c] = src[(size_t)c * 1024 + j];   // coalesced along n
  }
  __syncthreads();
  const int jt = t >> 3, r = t & 7;           // 8 threads per token
  float s = 0.f, ss = 0.f;
  for (int c = r; c < 384; c += 8) { float v = tile[jt][c]; s += v; ss += v * v; }
  s += __shfl_xor(s, 1); ss += __shfl_xor(ss, 1);
  s += __shfl_xor(s, 2); ss += __shfl_xor(ss, 2);
  s += __shfl_xor(s, 4); ss += __shfl_xor(ss, 4);
  const float mean = s * (1.f / 384.f);
  const float var  = ss * (1.f / 384.f) - mean * mean;  // ddof=0
  if (r == 0) { mu_s[jt] = mean; rs_s[jt] = rsqrtf(var + 1e-5f); }
  __syncthreads();
  for (int q = t; q < 3072; q += 256) {       // 32 tokens x 96 ushort4 quads
    int tok = q / 96, c4 = (q - tok * 96) * 4;
    float m = mu_s[tok], rv = rs_s[tok];
    float4 wv = *(const float4*)(gw + c4);
    float4 bv = *(const float4*)(gb + c4);
    u16* dst = out + (size_t)(b * 1024 + n0 + tok) * 384 + c4;
    ushort4 o{f2bf((tile[tok][c4 + 0] - m) * rv * wv.x + bv.x),
              f2bf((tile[tok][c4 + 1] - m) * rv * wv.y + bv.y),
              f2bf((tile[tok][c4 + 2] - m) * rv * wv.z + bv.z),
              f2bf((tile[tok][c4 + 3] - m) * rv * wv.w + bv.w)};
    *(ushort4*)dst = o;
  }
}

// ---- unified 128x128 / BK=32 / 4-wave bf16 GEMM, orientation-matched coalesced epilogues ----
// out[m,o] = sum_k A[m,k]*W[o,k] + bias.
// Orientation rule (verified r2/r5): mfma(X, Y) -> reg-dim indexes X, l16 indexes Y.
// EPI 0: QK of padded QKV (cols 0..1023), NON-swapped (l16 = col -> d contiguous)
// EPI 2: GELU -> bf16 row-major [16384][1536], NON-swapped (l16 = col contiguous)  [fc1]
// EPI 4: V -> Vt [bh,64,n], SWAPPED (l16 = token -> n contiguous)
// EPI 1: += resid (x) -> (B,C,N) f32, SWAPPED (l16 = token -> n contiguous)        [proj]
// EPI 3: += resid (y1t) -> d_out (B,C,N) f32, SWAPPED                              [fc2]
template<int EPI>
__global__ __launch_bounds__(256, 4) void gemm_kernel(
    const u16* __restrict__ A, const u16* __restrict__ W,
    const float* __restrict__ bias, float* __restrict__ outf,
    u16* __restrict__ outh, const float* __restrict__ resid, int K) {
  constexpr bool SWAP = (EPI == 1 || EPI == 3 || EPI == 4);
  __shared__ u16 sA[2][4096], sB[2][4096];  // 128x32 bf16 each, double buffered (32 KiB)
  int bx, by; xcd_remap(bx, by);
  const int m0 = bx * 128;
  const int n0 = (EPI == 4 ? 1024 : 0) + by * 128;
  const int wv = threadIdx.x >> 6, lane = threadIdx.x & 63;
  const int wm = (wv >> 1) * 64, wn = (wv & 1) * 64;
  const int l16 = lane & 15, lg = lane >> 4;
  const int rsw = (lg ^ (l16 & 3)) << 4;     // read-side swizzle (64B rows, 4 x 16B slots)

  f32x4 acc[4][4];
#pragma unroll
  for (int i = 0; i < 4; ++i)
#pragma unroll
    for (int jj = 0; jj < 4; ++jj) acc[i][jj] = f32x4{0.f, 0.f, 0.f, 0.f};

  const int nk = K >> 5;
  auto stage = [&](int buf, int kt) {
    const u16* Ab = A + (size_t)m0 * K + kt * 32;
    const u16* Wb = W + (size_t)n0 * K + kt * 32;
#pragma unroll
    for (int i = 0; i < 2; ++i) {
      int cb = i * 256 + wv * 64;            // wave-uniform chunk base
      int c = cb + lane;
      int row = c >> 2, sl = (c & 3) ^ (row & 3);   // inverse swizzle on SOURCE
      async16(Ab + (size_t)row * K + sl * 8, &sA[buf][cb * 8]);
      async16(Wb + (size_t)row * K + sl * 8, &sB[buf][cb * 8]);
    }
  };
  stage(0, 0);
  int buf = 0;
  for (int kt = 0; kt < nk; ++kt) {
    asm volatile("s_waitcnt vmcnt(0)" ::: "memory");
    __builtin_amdgcn_s_barrier();
    if (kt + 1 < nk) stage(buf ^ 1, kt + 1);
    bf16x8 av[4], bv[4];
#pragma unroll
    for (int f = 0; f < 4; ++f) {
      av[f] = *(const bf16x8*)((const char*)&sA[buf][0] + (wm + f * 16 + l16) * 64 + rsw);
      bv[f] = *(const bf16x8*)((const char*)&sB[buf][0] + (wn + f * 16 + l16) * 64 + rsw);
    }
    __builtin_amdgcn_s_setprio(1);
#pragma unroll
    for (int mf = 0; mf < 4; ++mf)
#pragma unroll
      for (int nf = 0; nf < 4; ++nf) {
        if constexpr (SWAP)
          acc[mf][nf] = __builtin_amdgcn_mfma_f32_16x16x32_bf16(bv[nf], av[mf], acc[mf][nf], 0, 0, 0);
        else
          acc[mf][nf] = __builtin_amdgcn_mfma_f32_16x16x32_bf16(av[mf], bv[nf], acc[mf][nf], 0, 0, 0);
      }
    __builtin_amdgcn_s_setprio(0);
    buf ^= 1;
  }

  if constexpr (!SWAP) {
    // reg-dim = tokens (4 consecutive), l16 = W col (fast output dim)
#pragma unroll
    for (int mf = 0; mf < 4; ++mf) {
      const int mm = m0 + wm + mf * 16 + lg * 4;    // token base
      const int b = mm >> 10, nnb = mm & 1023;
#pragma unroll
      for (int nf = 0; nf < 4; ++nf) {
        const int col = n0 + wn + nf * 16 + l16;
        f32x4 v = acc[mf][nf];
        const float bs = bias[col];
        if constexpr (EPI == 0) {  // Q/K [bh,n,64]: lanes cover 16 consecutive d (32B)
          const int which = col >> 9, h = (col >> 6) & 7, d0 = col & 63;
          size_t base = (size_t)which * QKSZ + (((size_t)(b * 8 + h)) << 16) + (size_t)nnb * 64 + d0;
#pragma unroll
          for (int rr = 0; rr < 4; ++rr) outh[base + (size_t)rr * 64] = f2bf(v[rr] + bs);
        } else {  // EPI 2: GELU, row-major [token][1536]: lanes 32B contiguous
#pragma unroll
          for (int rr = 0; rr < 4; ++rr)
            outh[(size_t)(mm + rr) * 1536 + col] = f2bf(gelu_f(v[rr] + bs));
        }
      }
    }
  } else {
    // reg-dim = W cols (4 consecutive), l16 = token (fast output dim n)
#pragma unroll
    for (int mf = 0; mf < 4; ++mf) {
      const int token = m0 + wm + mf * 16 + l16;
      const int b = token >> 10, nn = token & 1023;
#pragma unroll
      for (int nf = 0; nf < 4; ++nf) {
        const int colb = n0 + wn + nf * 16 + lg * 4;
        f32x4 v = acc[mf][nf];
        float4 bb = *(const float4*)(bias + colb);
        if constexpr (EPI == 4) {  // Vt [bh,d,n]: lanes cover 16 consecutive n (32B)
#pragma unroll
          for (int rr = 0; rr < 4; ++rr) {
            const int col = colb + rr, h = (col >> 6) & 7, d = col & 63;
            outh[2ull * QKSZ + (((size_t)((b * 8 + h) * 64 + d)) << 10) + nn] =
                f2bf(v[rr] + ((const float*)&bb)[rr]);
          }
        } else {  // EPI 1 / 3: (B,C,N) f32 residual add: lanes 64B contiguous
#pragma unroll
          for (int rr = 0; rr < 4; ++rr) {
            const int col = colb + rr;
            size_t idx = (((size_t)(b * 384 + col)) << 10) + nn;
            outf[idx] = v[rr] + ((const float*)&bb)[rr] + resid[idx];
          }
        }
      }
    }
  }
}

// ---- flash attention, 32x32 MFMA swapped-QK in-register softmax (T12 pattern) ----
// 1024 blocks = 128 (b,h) x 8 q-tiles of 128 rows. 4 waves, 32 q-rows each. KV tile = 64.
// S^T = mfma32(K, Q): lane holds full P-row (q = lane&31) -> in-lane softmax, no LDS P.
// P -> bf16 A-frags via v_cvt_pk_bf16_f32 + v_permlane32_swap_b32.
__global__ __launch_bounds__(256, 3) void attn_kernel(
    const u16* __restrict__ Qg, const u16* __restrict__ Kg,
    const u16* __restrict__ Vtg, u16* __restrict__ outp) {
  __shared__ u16 Ks[2][4096];
  __shared__ u16 Vs[2][4096];
  __shared__ u16 Qs[8192];                          // 128 x 64
  const int orig = blockIdx.x;
  const int swz = (orig & 7) * 128 + (orig >> 3);   // XCD swizzle: 8 q-tiles of a bh share an XCD
  const int bh = swz >> 3, qt = swz & 7;
  const int w = threadIdx.x >> 6, lane = threadIdx.x & 63;
  const int l31 = lane & 31, hi = lane >> 5;

  const u16* kbase = Kg + (size_t)bh * 65536;
  const u16* vbase = Vtg + (size_t)bh * 65536;

  auto stageKV = [&](int buf, int kv) {
#pragma unroll
    for (int i = 0; i < 2; ++i) {
      int cb = (i * 4 + w) * 64;
      int ck = cb + lane;
      int g  = ck ^ ((ck >> 3) & 7);              // inverse swizzle on the SOURCE
      async16(kbase + (size_t)kv * 4096 + g * 8, &Ks[buf][cb * 8]);
      async16(vbase + (size_t)(g >> 3) * 1024 + kv * 64 + (g & 7) * 8, &Vs[buf][cb * 8]);
    }
  };

  { // stage Q tile 128x64 (contiguous in global), swizzled
    const u16* src = Qg + (size_t)(bh * 1024 + qt * 128) * 64;
#pragma unroll
    for (int i = 0; i < 4; ++i) {
      int cb = (i * 4 + w) * 64;
      int ck = cb + lane;
      int g  = ck ^ ((ck >> 3) & 7);
      async16(src + g * 8, &Qs[cb * 8]);
    }
  }
  stageKV(0, 0);
  asm volatile("s_waitcnt vmcnt(0)" ::: "memory");
  __builtin_amdgcn_s_barrier();

  // Q fragments (B-operand): qf[ds] = Q[q = w*32+l31][d = 16ds+8hi .. +7]
  bf16x8 qf[4];
#pragma unroll
  for (int ds = 0; ds < 4; ++ds)
    qf[ds] = *lds_swz(Qs, w * 32 + l31, ds * 32 + hi * 16);

  f32x16 out0 = zero16(), out1 = zero16();
  float ls0 = 0.f, ls1 = 0.f;

  int buf = 0;
  for (int kv = 0; kv < 16; ++kv) {
    if (kv + 1 < 16) stageKV(buf ^ 1, kv + 1);    // loads fly over this tile's compute

    // --- QK^T (swapped): sacc[kvf] = S^T for kv rows kvf*32..+31, col q = l31 ---
    f32x16 sacc0 = zero16(), sacc1 = zero16();
    __builtin_amdgcn_s_setprio(1);
#pragma unroll
    for (int ds = 0; ds < 4; ++ds) {
      bf16x8 kf0 = *lds_swz(Ks[buf], l31,      ds * 32 + hi * 16);
      bf16x8 kf1 = *lds_swz(Ks[buf], 32 + l31, ds * 32 + hi * 16);
      sacc0 = __builtin_amdgcn_mfma_f32_32x32x16_bf16(kf0, qf[ds], sacc0, 0, 0, 0);
      sacc1 = __builtin_amdgcn_mfma_f32_32x32x16_bf16(kf1, qf[ds], sacc1, 0, 0, 0);
    }
    __builtin_amdgcn_s_setprio(0);

    // --- softmax numerator in-lane: p = exp(S); pack pairs to bf16 ---
    unsigned int c0[8], c1[8];
#pragma unroll
    for (int i = 0; i < 8; ++i) {
      float a = __expf(sacc0[2 * i]), b = __expf(sacc0[2 * i + 1]);
      ls0 += a + b;
      unsigned int pk;
      asm("v_cvt_pk_bf16_f32 %0, %1, %2" : "=v"(pk) : "v"(a), "v"(b));
      c0[i] = pk;
    }
#pragma unroll
    for (int i = 0; i < 8; ++i) {
      float a = __expf(sacc1[2 * i]), b = __expf(sacc1[2 * i + 1]);
      ls1 += a + b;
      unsigned int pk;
      asm("v_cvt_pk_bf16_f32 %0, %1, %2" : "=v"(pk) : "v"(a), "v"(b));
      c1[i] = pk;
    }

    // --- PV: A-frag assembly via permlane32_swap, B = Vt rows (d on l31) ---
#pragma unroll
    for (int m = 0; m < 4; ++m) {
      unsigned int a0 = (m < 2) ? c0[(m & 1) * 4 + 0] : c1[(m & 1) * 4 + 0];
      unsigned int b0 = (m < 2) ? c0[(m & 1) * 4 + 2] : c1[(m & 1) * 4 + 2];
      unsigned int a1 = (m < 2) ? c0[(m & 1) * 4 + 1] : c1[(m & 1) * 4 + 1];
      unsigned int b1 = (m < 2) ? c0[(m & 1) * 4 + 3] : c1[(m & 1) * 4 + 3];
      asm volatile("v_permlane32_swap_b32 %0, %1" : "+v"(a0), "+v"(b0));
      asm volatile("v_permlane32_swap_b32 %0, %1" : "+v"(a1), "+v"(b1));
      union { int4 i; bf16x8 v; } u;
      u.i = int4{(int)a0, (int)a1, (int)b0, (int)b1};
      bf16x8 pa = u.v;
      bf16x8 v0 = *lds_swz(Vs[buf], l31,      m * 32 + hi * 16);
      bf16x8 v1 = *lds_swz(Vs[buf], 32 + l31, m * 32 + hi * 16);
      __builtin_amdgcn_s_setprio(1);
      out0 = __builtin_amdgcn_mfma_f32_32x32x16_bf16(pa, v0, out0, 0, 0, 0);
      out1 = __builtin_amdgcn_mfma_f32_32x32x16_bf16(pa, v1, out1, 0, 0, 0);
      __builtin_amdgcn_s_setprio(0);
    }

    asm volatile("s_waitcnt vmcnt(0)" ::: "memory");
    __builtin_amdgcn_s_barrier();                  // next KV landed for ALL waves
    buf ^= 1;
  }

  // --- epilogue: full row-sum (combine hi halves), normalize, store d<48 ---
  float lf = ls0 + ls1;
  lf += __shfl_xor(lf, 32);
  const int b = bh >> 3, h = bh & 7;
#pragma unroll
  for (int r = 0; r < 16; ++r) {
    const int q = (r & 3) + 8 * (r >> 2) + 4 * hi;     // C/D row pattern
    const float inv = 1.f / __shfl(lf, q);             // lane q holds lsum of q-row
    const int token = qt * 128 + w * 32 + q;
    const size_t rowb = (size_t)(b * 1024 + token) * 384 + h * 48;
    outp[rowb + l31] = f2bf(out0[r] * inv);            // d = l31 (0..31)
    if (l31 < 16) outp[rowb + 32 + l31] = f2bf(out1[r] * inv);  // d = 32..47
  }
}

// ---- workspace layout (bytes) ----
constexpr size_t OFF_WQKVP = 0;          // 1536*384*2   = 1179648
constexpr size_t OFF_BIASP = 1179648;    // 1536*4      -> 1185792
constexpr size_t OFF_WPROJ = 1185792;    // 384*384*2   -> 1480704
constexpr size_t OFF_WFC1  = 1480704;    // 1536*384*2  -> 2660352
constexpr size_t OFF_WFC2  = 2660352;    // 384*1536*2  -> 3840000
constexpr size_t OFF_H     = 3840000;    // 16384*384*2 -> 16422912 (h1, later h2)
constexpr size_t OFF_QKV   = 16422912;   // 3*QKSZ*2    -> 66754560 (later f1)
constexpr size_t OFF_AO    = 66754560;   // 16384*384*2 -> 79337472
constexpr size_t OFF_Y1T   = 79337472;   // 16384*384*4 -> 104503296 total

extern "C" void kernel_launch(void* const* d_in, const int* in_sizes, int n_in,
                              void* d_out, int out_size, void* d_ws, size_t ws_size,
                              hipStream_t stream) {
  (void)in_sizes; (void)n_in; (void)out_size; (void)ws_size;
  const float* x     = (const float*)d_in[0];
  const float* ln1w  = (const float*)d_in[1];
  const float* ln1b  = (const float*)d_in[2];
  const float* qkvw  = (const float*)d_in[3];
  const float* qkvbi = (const float*)d_in[4];
  const float* projw = (const float*)d_in[5];
  const float* projb = (const float*)d_in[6];
  const float* ln2w  = (const float*)d_in[7];
  const float* ln2b  = (const float*)d_in[8];
  const float* fc1w  = (const float*)d_in[9];
  const float* fc1b  = (const float*)d_in[10];
  const float* fc2w  = (const float*)d_in[11];
  const float* fc2b  = (const float*)d_in[12];

  char* ws = (char*)d_ws;
  u16*   wqkvp = (u16*)(ws + OFF_WQKVP);
  float* biasp = (float*)(ws + OFF_BIASP);
  u16*   wproj = (u16*)(ws + OFF_WPROJ);
  u16*   wfc1  = (u16*)(ws + OFF_WFC1);
  u16*   wfc2  = (u16*)(ws + OFF_WFC2);
  u16*   h1    = (u16*)(ws + OFF_H);     // also h2
  u16*   qkvs  = (u16*)(ws + OFF_QKV);   // Q | K | Vt ; later f1
  u16*   f1    = qkvs;
  u16*   ao    = (u16*)(ws + OFF_AO);
  float* y1t   = (float*)(ws + OFF_Y1T);

  cvt_kernel<<<1874, 256, 0, stream>>>(qkvw, qkvbi, projw, fc1w, fc2w,
                                       wqkvp, biasp, wproj, wfc1, wfc2);

  dim3 lngrid(32, 16);
  ln_kernel<<<lngrid, 256, 0, stream>>>(x, ln1w, ln1b, h1);

  // QKV: QK non-swapped (d on l16), V swapped (n on l16); pads written as zeros
  gemm_kernel<0><<<dim3(128, 8), 256, 0, stream>>>(h1, wqkvp, biasp, nullptr, qkvs, nullptr, 384);
  gemm_kernel<4><<<dim3(128, 4), 256, 0, stream>>>(h1, wqkvp, biasp, nullptr, qkvs, nullptr, 384);

  attn_kernel<<<dim3(1024), 256, 0, stream>>>(qkvs, qkvs + QKSZ, qkvs + 2 * QKSZ, ao);

  gemm_kernel<1><<<dim3(128, 3), 256, 0, stream>>>(ao, wproj, projb, y1t, nullptr, x, 384);

  ln_kernel<<<lngrid, 256, 0, stream>>>(y1t, ln2w, ln2b, h1 /*h2*/);

  gemm_kernel<2><<<dim3(128, 12), 256, 0, stream>>>(h1, wfc1, fc1b, nullptr, f1, nullptr, 384);

  gemm_kernel<3><<<dim3(128, 3), 256, 0, stream>>>(f1, wfc2, fc2b, (float*)d_out, nullptr, y1t, 1536);
}